// Round 1
// baseline (788.871 us; speedup 1.0000x reference)
//
#include <hip/hip_runtime.h>
#include <math.h>
#include <float.h>

#define NBG 128      // graphs
#define NND 512      // nodes per graph
#define KNN 6
#define NB_TOT (NBG*NND)
#define HF 256

// ---------------------------------------------------------------------------
// kNN: one block per graph. pos staged in LDS, each thread handles 2 nodes,
// keeps a sorted top-6 (ascending d2) in registers. Strict '<' preserves
// lower-index-wins on ties (matches jax.lax.top_k stability).
// ---------------------------------------------------------------------------
__global__ __launch_bounds__(256) void knn_kernel(const float* __restrict__ pos,
                                                  int* __restrict__ nbr)
{
    int g = blockIdx.x, tid = threadIdx.x;
    __shared__ float px[NND], py[NND], pz[NND], sq[NND];
    const float* pg = pos + (size_t)g * NND * 3;
    for (int idx = tid; idx < NND*3; idx += 256) {
        float v = pg[idx];
        int n = idx / 3, d = idx - n*3;
        if (d == 0) px[n] = v; else if (d == 1) py[n] = v; else pz[n] = v;
    }
    __syncthreads();
    for (int n = tid; n < NND; n += 256) sq[n] = px[n]*px[n] + py[n]*py[n] + pz[n]*pz[n];
    __syncthreads();
    #pragma unroll
    for (int p = 0; p < 2; ++p) {
        int i = tid + p*256;
        float xi = px[i], yi = py[i], zi = pz[i], si = sq[i];
        float bd[KNN]; int bi[KNN];
        #pragma unroll
        for (int q = 0; q < KNN; ++q) { bd[q] = FLT_MAX; bi[q] = 0; }
        for (int j = 0; j < NND; ++j) {
            if (j == i) continue;
            float d2 = si + sq[j] - 2.0f*(xi*px[j] + yi*py[j] + zi*pz[j]);
            if (d2 < bd[KNN-1]) {
                float vd = d2; int vi = j;
                #pragma unroll
                for (int q = 0; q < KNN; ++q) {
                    if (vd < bd[q]) {
                        float td = bd[q]; int ti = bi[q];
                        bd[q] = vd; bi[q] = vi; vd = td; vi = ti;
                    }
                }
            }
        }
        int base = (g*NND + i)*KNN;
        #pragma unroll
        for (int q = 0; q < KNN; ++q) nbr[base+q] = g*NND + bi[q];
    }
}

// ---------------------------------------------------------------------------
// Aggregate concat(x,pos): out[i] = c1*sum_nbr h0[j] + c2*h0[i], stride 132
// (131 features + 1 zero pad). One thread per output float4 (33 per node).
// ---------------------------------------------------------------------------
__global__ __launch_bounds__(256) void agg_first(const float* __restrict__ x,
                                                 const float* __restrict__ pos,
                                                 const int* __restrict__ nbr,
                                                 float* __restrict__ out)
{
    int gid = blockIdx.x*256 + threadIdx.x;   // NB_TOT*33 threads
    int i = gid / 33, c = gid - i*33;
    const float rs = 1.0f/sqrtf(7.0f);
    const float c1 = rs*rs;
    const float c2 = 1.0f/7.0f;
    int j[KNN];
    #pragma unroll
    for (int q = 0; q < KNN; ++q) j[q] = nbr[i*KNN + q];
    float4 r;
    if (c < 32) {
        const float4* x4 = (const float4*)x;
        float4 s = x4[(size_t)i*32 + c];
        float ax = 0.f, ay = 0.f, az = 0.f, aw = 0.f;
        #pragma unroll
        for (int q = 0; q < KNN; ++q) {
            float4 t = x4[(size_t)j[q]*32 + c];
            ax += t.x; ay += t.y; az += t.z; aw += t.w;
        }
        r.x = ax*c1 + s.x*c2; r.y = ay*c1 + s.y*c2;
        r.z = az*c1 + s.z*c2; r.w = aw*c1 + s.w*c2;
    } else {
        float sx = pos[(size_t)i*3+0], sy = pos[(size_t)i*3+1], sz = pos[(size_t)i*3+2];
        float ax = 0.f, ay = 0.f, az = 0.f;
        #pragma unroll
        for (int q = 0; q < KNN; ++q) {
            ax += pos[(size_t)j[q]*3+0];
            ay += pos[(size_t)j[q]*3+1];
            az += pos[(size_t)j[q]*3+2];
        }
        r.x = ax*c1 + sx*c2; r.y = ay*c1 + sy*c2; r.z = az*c1 + sz*c2; r.w = 0.f;
    }
    ((float4*)out)[(size_t)i*33 + c] = r;
}

// ---------------------------------------------------------------------------
// Aggregate 256-dim h: out[i] = c1*sum_nbr h[j] + c2*h[i]. float4 per thread.
// ---------------------------------------------------------------------------
__global__ __launch_bounds__(256) void agg_h(const float* __restrict__ h,
                                             const int* __restrict__ nbr,
                                             float* __restrict__ out)
{
    int gid = blockIdx.x*256 + threadIdx.x;   // NB_TOT*64 threads
    int i = gid >> 6, c = gid & 63;
    const float rs = 1.0f/sqrtf(7.0f);
    const float c1 = rs*rs;
    const float c2 = 1.0f/7.0f;
    const float4* h4 = (const float4*)h;
    int j[KNN];
    #pragma unroll
    for (int q = 0; q < KNN; ++q) j[q] = nbr[i*KNN + q];
    float4 s = h4[(size_t)i*64 + c];
    float ax = 0.f, ay = 0.f, az = 0.f, aw = 0.f;
    #pragma unroll
    for (int q = 0; q < KNN; ++q) {
        float4 t = h4[(size_t)j[q]*64 + c];
        ax += t.x; ay += t.y; az += t.z; aw += t.w;
    }
    float4 r;
    r.x = ax*c1 + s.x*c2; r.y = ay*c1 + s.y*c2;
    r.z = az*c1 + s.z*c2; r.w = aw*c1 + s.w*c2;
    ((float4*)out)[(size_t)i*64 + c] = r;
}

// ---------------------------------------------------------------------------
// Fused GEMM + bias + BN + ReLU.  C[M,256] = relu(bn(A[M,K] @ W[K,256] + b)).
// BM=64, BN=256, BK=32. 256 threads; thread (tr=tid>>5, tc=tid&31) computes
// rows tr*8..tr*8+7 and cols {tc*4..tc*4+3, 128+tc*4..128+tc*4+3}.
// A is transposed into LDS so inner-loop A reads are wave broadcasts.
// ---------------------------------------------------------------------------
__global__ __launch_bounds__(256,2) void gemm_bn_relu(
    const float* __restrict__ A, int lda, int K,
    const float* __restrict__ W,
    const float* __restrict__ bias,
    const float* __restrict__ gam, const float* __restrict__ bet,
    const float* __restrict__ mu,  const float* __restrict__ var,
    float* __restrict__ out)
{
    __shared__ float As[32][68];    // [k][row], padded
    __shared__ float Ws[32][256];   // [k][col]
    const int tid = threadIdx.x;
    const int tc = tid & 31, tr = tid >> 5;
    const int row0 = blockIdx.x * 64;

    float acc[8][8];
    #pragma unroll
    for (int i2 = 0; i2 < 8; ++i2)
        #pragma unroll
        for (int j2 = 0; j2 < 8; ++j2) acc[i2][j2] = 0.f;

    for (int k0 = 0; k0 < K; k0 += 32) {
        // stage A tile (64 rows x 32 k), transposed
        #pragma unroll
        for (int p = 0; p < 2; ++p) {
            int idx = tid + 256*p;
            int r = idx >> 3, kk = (idx & 7) * 4;
            int gk = k0 + kk;
            float4 av = make_float4(0.f, 0.f, 0.f, 0.f);
            if (gk < K) av = *(const float4*)&A[(size_t)(row0 + r)*lda + gk];
            As[kk+0][r] = av.x; As[kk+1][r] = av.y;
            As[kk+2][r] = av.z; As[kk+3][r] = av.w;
        }
        // stage W tile (32 k x 256 cols)
        #pragma unroll
        for (int p = 0; p < 8; ++p) {
            int idx = tid + 256*p;
            int kk = idx >> 6, c4 = idx & 63;
            int gk = k0 + kk;
            float4 wv = make_float4(0.f, 0.f, 0.f, 0.f);
            if (gk < K) wv = *(const float4*)&W[(size_t)gk*256 + c4*4];
            *(float4*)&Ws[kk][c4*4] = wv;
        }
        __syncthreads();
        #pragma unroll
        for (int kk = 0; kk < 32; ++kk) {
            float a[8], w[8];
            *(float4*)&a[0] = *(const float4*)&As[kk][tr*8];
            *(float4*)&a[4] = *(const float4*)&As[kk][tr*8 + 4];
            *(float4*)&w[0] = *(const float4*)&Ws[kk][tc*4];
            *(float4*)&w[4] = *(const float4*)&Ws[kk][128 + tc*4];
            #pragma unroll
            for (int i2 = 0; i2 < 8; ++i2)
                #pragma unroll
                for (int j2 = 0; j2 < 8; ++j2)
                    acc[i2][j2] = fmaf(a[i2], w[j2], acc[i2][j2]);
        }
        __syncthreads();
    }

    // epilogue: out = relu((acc + bias - mu) * (gam/sqrt(var+eps)) + bet)
    float sc[8], sh[8];
    #pragma unroll
    for (int j2 = 0; j2 < 8; ++j2) {
        int c = (j2 < 4) ? (tc*4 + j2) : (128 + tc*4 + (j2-4));
        float s = gam[c] / sqrtf(var[c] + 1e-5f);
        sc[j2] = s;
        sh[j2] = bet[c] + (bias[c] - mu[c]) * s;
    }
    #pragma unroll
    for (int i2 = 0; i2 < 8; ++i2) {
        int r = row0 + tr*8 + i2;
        float o[8];
        #pragma unroll
        for (int j2 = 0; j2 < 8; ++j2)
            o[j2] = fmaxf(acc[i2][j2]*sc[j2] + sh[j2], 0.f);
        *(float4*)&out[(size_t)r*256 + tc*4]       = make_float4(o[0], o[1], o[2], o[3]);
        *(float4*)&out[(size_t)r*256 + 128 + tc*4] = make_float4(o[4], o[5], o[6], o[7]);
    }
}

// ---------------------------------------------------------------------------
// Readout: per-graph gate -> softmax -> weighted sum -> heads.
// One block (256 threads) per graph.
// ---------------------------------------------------------------------------
__device__ __forceinline__ float blk_sum256(float v, volatile float* red)
{
    #pragma unroll
    for (int o = 32; o > 0; o >>= 1) v += __shfl_xor(v, o, 64);
    __syncthreads();
    if ((threadIdx.x & 63) == 0) red[threadIdx.x >> 6] = v;
    __syncthreads();
    return (red[0] + red[1]) + (red[2] + red[3]);
}

__global__ __launch_bounds__(256) void readout_kernel(
    const float* __restrict__ h3,
    const float* __restrict__ gate_w, const float* __restrict__ gate_b,
    const float* __restrict__ aff_w,  const float* __restrict__ aff_b,
    const float* __restrict__ rl_w1,  const float* __restrict__ rl_b1,
    const float* __restrict__ rl_w2,  const float* __restrict__ rl_b2,
    float* __restrict__ out)
{
    int g = blockIdx.x, tid = threadIdx.x;
    __shared__ float attn[NND];
    __shared__ float gemb[HF];
    __shared__ float gw[HF];
    __shared__ float red[4];

    gw[tid] = gate_w[tid];
    __syncthreads();
    const float* hb = h3 + (size_t)g * NND * HF;

    // gate = relu(h3 @ gate_w + gate_b), 2 nodes per thread
    float gv[2];
    #pragma unroll
    for (int p = 0; p < 2; ++p) {
        const float4* row = (const float4*)(hb + (size_t)(tid + p*256)*HF);
        float s = 0.f;
        #pragma unroll 8
        for (int c = 0; c < 64; ++c) {
            float4 a = row[c];
            float4 w = *(const float4*)&gw[c*4];
            s += a.x*w.x + a.y*w.y + a.z*w.z + a.w*w.w;
        }
        s += gate_b[0];
        gv[p] = fmaxf(s, 0.f);
    }

    // softmax over 512 gates
    float m = fmaxf(gv[0], gv[1]);
    #pragma unroll
    for (int o = 32; o > 0; o >>= 1) m = fmaxf(m, __shfl_xor(m, o, 64));
    if ((tid & 63) == 0) red[tid >> 6] = m;
    __syncthreads();
    m = fmaxf(fmaxf(red[0], red[1]), fmaxf(red[2], red[3]));
    float e0 = expf(gv[0] - m), e1 = expf(gv[1] - m);
    float S = blk_sum256(e0 + e1, red);
    attn[tid]       = e0 / S;
    attn[tid + 256] = e1 / S;
    __syncthreads();

    // gemb[f] = sum_n attn[n] * h3[n][f]   (f = tid, coalesced)
    float acc = 0.f;
    #pragma unroll 4
    for (int n = 0; n < NND; ++n)
        acc = fmaf(attn[n], hb[(size_t)n*HF + tid], acc);
    gemb[tid] = acc;
    __syncthreads();

    // affinity = gemb @ aff_w + aff_b
    float sa = blk_sum256(acc * aff_w[tid], red);
    if (tid == 0) out[g] = sa + aff_b[0];

    // pose = relu(gemb @ rl_w1 + rl_b1) @ rl_w2 + rl_b2
    float t = rl_b1[tid];
    #pragma unroll 4
    for (int k2 = 0; k2 < HF; ++k2)
        t = fmaf(gemb[k2], rl_w1[(size_t)k2*HF + tid], t);
    t = fmaxf(t, 0.f);
    float s0 = blk_sum256(t * rl_w2[(size_t)tid*3 + 0], red);
    if (tid == 0) out[128 + g*3 + 0] = s0 + rl_b2[0];
    float s1 = blk_sum256(t * rl_w2[(size_t)tid*3 + 1], red);
    if (tid == 0) out[128 + g*3 + 1] = s1 + rl_b2[1];
    float s2 = blk_sum256(t * rl_w2[(size_t)tid*3 + 2], red);
    if (tid == 0) out[128 + g*3 + 2] = s2 + rl_b2[2];
}

// ---------------------------------------------------------------------------
extern "C" void kernel_launch(void* const* d_in, const int* in_sizes, int n_in,
                              void* d_out, int out_size, void* d_ws, size_t ws_size,
                              hipStream_t stream)
{
    const float* x      = (const float*)d_in[0];
    const float* pos    = (const float*)d_in[1];
    const float* W1     = (const float*)d_in[2];
    const float* b1     = (const float*)d_in[3];
    const float* W2     = (const float*)d_in[4];
    const float* b2     = (const float*)d_in[5];
    const float* W3     = (const float*)d_in[6];
    const float* b3     = (const float*)d_in[7];
    const float* g1     = (const float*)d_in[8];
    const float* be1    = (const float*)d_in[9];
    const float* m1     = (const float*)d_in[10];
    const float* v1     = (const float*)d_in[11];
    const float* g2     = (const float*)d_in[12];
    const float* be2    = (const float*)d_in[13];
    const float* m2     = (const float*)d_in[14];
    const float* v2     = (const float*)d_in[15];
    const float* g3     = (const float*)d_in[16];
    const float* be3    = (const float*)d_in[17];
    const float* m3     = (const float*)d_in[18];
    const float* v3     = (const float*)d_in[19];
    const float* gate_w = (const float*)d_in[20];
    const float* gate_b = (const float*)d_in[21];
    const float* aff_w  = (const float*)d_in[22];
    const float* aff_b  = (const float*)d_in[23];
    const float* rl_w1  = (const float*)d_in[24];
    const float* rl_b1  = (const float*)d_in[25];
    const float* rl_w2  = (const float*)d_in[26];
    const float* rl_b2  = (const float*)d_in[27];
    float* out = (float*)d_out;

    char* wsb = (char*)d_ws;
    int*   nbr = (int*)wsb;                                   // NB_TOT*6 ints
    float* P1  = (float*)(wsb + (size_t)NB_TOT*KNN*4);        // 67.1 MB pool
    float* P2  = P1 + (size_t)NB_TOT*HF;                      // 67.1 MB pool

    knn_kernel<<<NBG, 256, 0, stream>>>(pos, nbr);
    // ha0 = agg(concat(x,pos))  [NB,132]
    agg_first<<<(NB_TOT*33)/256, 256, 0, stream>>>(x, pos, nbr, P1);
    // h1 = relu(bn1(ha0 @ W1 + b1))
    gemm_bn_relu<<<NB_TOT/64, 256, 0, stream>>>(P1, 132, 131, W1, b1, g1, be1, m1, v1, P2);
    // ha1 = agg(h1)
    agg_h<<<(NB_TOT*64)/256, 256, 0, stream>>>(P2, nbr, P1);
    // h2 = relu(bn2(ha1 @ W2 + b2))
    gemm_bn_relu<<<NB_TOT/64, 256, 0, stream>>>(P1, 256, 256, W2, b2, g2, be2, m2, v2, P2);
    // ha2 = agg(h2)
    agg_h<<<(NB_TOT*64)/256, 256, 0, stream>>>(P2, nbr, P1);
    // h3 = relu(bn3(ha2 @ W3 + b3))
    gemm_bn_relu<<<NB_TOT/64, 256, 0, stream>>>(P1, 256, 256, W3, b3, g3, be3, m3, v3, P2);
    // readout
    readout_kernel<<<NBG, 256, 0, stream>>>(P2, gate_w, gate_b, aff_w, aff_b,
                                            rl_w1, rl_b1, rl_w2, rl_b2, out);
}

// Round 2
// 611.879 us; speedup vs baseline: 1.2893x; 1.2893x over previous
//
#include <hip/hip_runtime.h>
#include <math.h>
#include <float.h>

#define NBG 128      // graphs
#define NND 512      // nodes per graph
#define KNN 6
#define NB_TOT (NBG*NND)
#define HF 256

// ---------------------------------------------------------------------------
// kNN v2: 4 blocks per graph (512 blocks total), 2 threads per node.
// Each thread scans 256 candidates keeping a sorted top-6, then lane-pairs
// merge via shfl_xor + min-trick + unrolled sorting network.
// Total order (d2 asc, idx asc) matches jax.lax.top_k tie semantics.
// ---------------------------------------------------------------------------
__global__ __launch_bounds__(256) void knn_kernel(const float* __restrict__ pos,
                                                  int* __restrict__ nbr)
{
    const int blk = blockIdx.x;           // 512 blocks
    const int g = blk >> 2;
    const int chunk = (blk & 3) * 128;
    const int tid = threadIdx.x;
    const int node = chunk + (tid >> 1);  // local node id within graph
    const int sub = tid & 1;              // which half of candidates

    __shared__ float4 p4[NND];            // (x, y, z, |p|^2)
    const float* pg = pos + (size_t)g * NND * 3;
    for (int n = tid; n < NND; n += 256) {
        float x = pg[n*3+0], y = pg[n*3+1], z = pg[n*3+2];
        p4[n] = make_float4(x, y, z, x*x + y*y + z*z);
    }
    __syncthreads();

    const float4 pi = p4[node];
    float bd[KNN]; int bi[KNN];
    #pragma unroll
    for (int q = 0; q < KNN; ++q) { bd[q] = FLT_MAX; bi[q] = 0x7fffffff; }

    const int j0 = sub * 256;
    for (int j = j0; j < j0 + 256; ++j) {
        float4 pj = p4[j];
        float d2 = pi.w + pj.w - 2.0f*(pi.x*pj.x + pi.y*pj.y + pi.z*pj.z);
        if (j != node && d2 < bd[KNN-1]) {
            float vd = d2; int vi = j;
            #pragma unroll
            for (int q = 0; q < KNN; ++q) {
                if (vd < bd[q]) {
                    float td = bd[q]; int ti = bi[q];
                    bd[q] = vd; bi[q] = vi; vd = td; vi = ti;
                }
            }
        }
    }

    // exchange sorted top-6 with partner lane (tid^1, same wave)
    float od[KNN]; int oi[KNN];
    #pragma unroll
    for (int q = 0; q < KNN; ++q) {
        od[q] = __shfl_xor(bd[q], 1);
        oi[q] = __shfl_xor(bi[q], 1);
    }
    // min-trick: smallest 6 of the union under total order (d, idx)
    float ld[KNN]; int li[KNN];
    #pragma unroll
    for (int q = 0; q < KNN; ++q) {
        float ad = bd[q], xd = od[KNN-1-q];
        int   ai = bi[q], xi = oi[KNN-1-q];
        bool t = (ad < xd) || (ad == xd && ai < xi);
        ld[q] = t ? ad : xd;
        li[q] = t ? ai : xi;
    }
    // bubble sorting network (15 CEs, static indices)
    #define CE(a,b) { \
        bool sw = (ld[b] < ld[a]) || (ld[b] == ld[a] && li[b] < li[a]); \
        float td = sw ? ld[b] : ld[a]; float ud = sw ? ld[a] : ld[b];   \
        int   ti = sw ? li[b] : li[a]; int   ui = sw ? li[a] : li[b];   \
        ld[a] = td; li[a] = ti; ld[b] = ud; li[b] = ui; }
    CE(0,1) CE(1,2) CE(2,3) CE(3,4) CE(4,5)
    CE(0,1) CE(1,2) CE(2,3) CE(3,4)
    CE(0,1) CE(1,2) CE(2,3)
    CE(0,1) CE(1,2)
    CE(0,1)
    #undef CE

    if (sub == 0) {
        int base = (g*NND + node)*KNN;
        #pragma unroll
        for (int q = 0; q < KNN; ++q) nbr[base+q] = g*NND + li[q];
    }
}

// ---------------------------------------------------------------------------
// Aggregate concat(x,pos): out[i] = c1*sum_nbr h0[j] + c2*h0[i], stride 132
// (131 features + 1 zero pad). One thread per output float4 (33 per node).
// ---------------------------------------------------------------------------
__global__ __launch_bounds__(256) void agg_first(const float* __restrict__ x,
                                                 const float* __restrict__ pos,
                                                 const int* __restrict__ nbr,
                                                 float* __restrict__ out)
{
    int gid = blockIdx.x*256 + threadIdx.x;   // NB_TOT*33 threads
    int i = gid / 33, c = gid - i*33;
    const float rs = 1.0f/sqrtf(7.0f);
    const float c1 = rs*rs;
    const float c2 = 1.0f/7.0f;
    int j[KNN];
    #pragma unroll
    for (int q = 0; q < KNN; ++q) j[q] = nbr[i*KNN + q];
    float4 r;
    if (c < 32) {
        const float4* x4 = (const float4*)x;
        float4 s = x4[(size_t)i*32 + c];
        float ax = 0.f, ay = 0.f, az = 0.f, aw = 0.f;
        #pragma unroll
        for (int q = 0; q < KNN; ++q) {
            float4 t = x4[(size_t)j[q]*32 + c];
            ax += t.x; ay += t.y; az += t.z; aw += t.w;
        }
        r.x = ax*c1 + s.x*c2; r.y = ay*c1 + s.y*c2;
        r.z = az*c1 + s.z*c2; r.w = aw*c1 + s.w*c2;
    } else {
        float sx = pos[(size_t)i*3+0], sy = pos[(size_t)i*3+1], sz = pos[(size_t)i*3+2];
        float ax = 0.f, ay = 0.f, az = 0.f;
        #pragma unroll
        for (int q = 0; q < KNN; ++q) {
            ax += pos[(size_t)j[q]*3+0];
            ay += pos[(size_t)j[q]*3+1];
            az += pos[(size_t)j[q]*3+2];
        }
        r.x = ax*c1 + sx*c2; r.y = ay*c1 + sy*c2; r.z = az*c1 + sz*c2; r.w = 0.f;
    }
    ((float4*)out)[(size_t)i*33 + c] = r;
}

// ---------------------------------------------------------------------------
// Aggregate 256-dim h: out[i] = c1*sum_nbr h[j] + c2*h[i]. float4 per thread.
// ---------------------------------------------------------------------------
__global__ __launch_bounds__(256) void agg_h(const float* __restrict__ h,
                                             const int* __restrict__ nbr,
                                             float* __restrict__ out)
{
    int gid = blockIdx.x*256 + threadIdx.x;   // NB_TOT*64 threads
    int i = gid >> 6, c = gid & 63;
    const float rs = 1.0f/sqrtf(7.0f);
    const float c1 = rs*rs;
    const float c2 = 1.0f/7.0f;
    const float4* h4 = (const float4*)h;
    int j[KNN];
    #pragma unroll
    for (int q = 0; q < KNN; ++q) j[q] = nbr[i*KNN + q];
    float4 s = h4[(size_t)i*64 + c];
    float ax = 0.f, ay = 0.f, az = 0.f, aw = 0.f;
    #pragma unroll
    for (int q = 0; q < KNN; ++q) {
        float4 t = h4[(size_t)j[q]*64 + c];
        ax += t.x; ay += t.y; az += t.z; aw += t.w;
    }
    float4 r;
    r.x = ax*c1 + s.x*c2; r.y = ay*c1 + s.y*c2;
    r.z = az*c1 + s.z*c2; r.w = aw*c1 + s.w*c2;
    ((float4*)out)[(size_t)i*64 + c] = r;
}

// ---------------------------------------------------------------------------
// Fused GEMM + bias + BN + ReLU.  C[M,256] = relu(bn(A[M,K] @ W[K,256] + b)).
// BM=64, BN=256, BK=32. 256 threads; thread (tr=tid>>5, tc=tid&31) computes
// rows tr*8..tr*8+7 and cols {tc*4..tc*4+3, 128+tc*4..128+tc*4+3}.
// A is transposed into LDS so inner-loop A reads are wave broadcasts.
// ---------------------------------------------------------------------------
__global__ __launch_bounds__(256,2) void gemm_bn_relu(
    const float* __restrict__ A, int lda, int K,
    const float* __restrict__ W,
    const float* __restrict__ bias,
    const float* __restrict__ gam, const float* __restrict__ bet,
    const float* __restrict__ mu,  const float* __restrict__ var,
    float* __restrict__ out)
{
    __shared__ float As[32][68];    // [k][row], padded
    __shared__ float Ws[32][256];   // [k][col]
    const int tid = threadIdx.x;
    const int tc = tid & 31, tr = tid >> 5;
    const int row0 = blockIdx.x * 64;

    float acc[8][8];
    #pragma unroll
    for (int i2 = 0; i2 < 8; ++i2)
        #pragma unroll
        for (int j2 = 0; j2 < 8; ++j2) acc[i2][j2] = 0.f;

    for (int k0 = 0; k0 < K; k0 += 32) {
        // stage A tile (64 rows x 32 k), transposed
        #pragma unroll
        for (int p = 0; p < 2; ++p) {
            int idx = tid + 256*p;
            int r = idx >> 3, kk = (idx & 7) * 4;
            int gk = k0 + kk;
            float4 av = make_float4(0.f, 0.f, 0.f, 0.f);
            if (gk < K) av = *(const float4*)&A[(size_t)(row0 + r)*lda + gk];
            As[kk+0][r] = av.x; As[kk+1][r] = av.y;
            As[kk+2][r] = av.z; As[kk+3][r] = av.w;
        }
        // stage W tile (32 k x 256 cols)
        #pragma unroll
        for (int p = 0; p < 8; ++p) {
            int idx = tid + 256*p;
            int kk = idx >> 6, c4 = idx & 63;
            int gk = k0 + kk;
            float4 wv = make_float4(0.f, 0.f, 0.f, 0.f);
            if (gk < K) wv = *(const float4*)&W[(size_t)gk*256 + c4*4];
            *(float4*)&Ws[kk][c4*4] = wv;
        }
        __syncthreads();
        #pragma unroll
        for (int kk = 0; kk < 32; ++kk) {
            float a[8], w[8];
            *(float4*)&a[0] = *(const float4*)&As[kk][tr*8];
            *(float4*)&a[4] = *(const float4*)&As[kk][tr*8 + 4];
            *(float4*)&w[0] = *(const float4*)&Ws[kk][tc*4];
            *(float4*)&w[4] = *(const float4*)&Ws[kk][128 + tc*4];
            #pragma unroll
            for (int i2 = 0; i2 < 8; ++i2)
                #pragma unroll
                for (int j2 = 0; j2 < 8; ++j2)
                    acc[i2][j2] = fmaf(a[i2], w[j2], acc[i2][j2]);
        }
        __syncthreads();
    }

    // epilogue: out = relu((acc + bias - mu) * (gam/sqrt(var+eps)) + bet)
    float sc[8], sh[8];
    #pragma unroll
    for (int j2 = 0; j2 < 8; ++j2) {
        int c = (j2 < 4) ? (tc*4 + j2) : (128 + tc*4 + (j2-4));
        float s = gam[c] / sqrtf(var[c] + 1e-5f);
        sc[j2] = s;
        sh[j2] = bet[c] + (bias[c] - mu[c]) * s;
    }
    #pragma unroll
    for (int i2 = 0; i2 < 8; ++i2) {
        int r = row0 + tr*8 + i2;
        float o[8];
        #pragma unroll
        for (int j2 = 0; j2 < 8; ++j2)
            o[j2] = fmaxf(acc[i2][j2]*sc[j2] + sh[j2], 0.f);
        *(float4*)&out[(size_t)r*256 + tc*4]       = make_float4(o[0], o[1], o[2], o[3]);
        *(float4*)&out[(size_t)r*256 + 128 + tc*4] = make_float4(o[4], o[5], o[6], o[7]);
    }
}

// ---------------------------------------------------------------------------
// Readout: per-graph gate -> softmax -> weighted sum -> heads.
// One block (256 threads) per graph.
// ---------------------------------------------------------------------------
__device__ __forceinline__ float blk_sum256(float v, volatile float* red)
{
    #pragma unroll
    for (int o = 32; o > 0; o >>= 1) v += __shfl_xor(v, o, 64);
    __syncthreads();
    if ((threadIdx.x & 63) == 0) red[threadIdx.x >> 6] = v;
    __syncthreads();
    return (red[0] + red[1]) + (red[2] + red[3]);
}

__global__ __launch_bounds__(256) void readout_kernel(
    const float* __restrict__ h3,
    const float* __restrict__ gate_w, const float* __restrict__ gate_b,
    const float* __restrict__ aff_w,  const float* __restrict__ aff_b,
    const float* __restrict__ rl_w1,  const float* __restrict__ rl_b1,
    const float* __restrict__ rl_w2,  const float* __restrict__ rl_b2,
    float* __restrict__ out)
{
    int g = blockIdx.x, tid = threadIdx.x;
    __shared__ float attn[NND];
    __shared__ float gemb[HF];
    __shared__ float gw[HF];
    __shared__ float red[4];

    gw[tid] = gate_w[tid];
    __syncthreads();
    const float* hb = h3 + (size_t)g * NND * HF;

    // gate = relu(h3 @ gate_w + gate_b), 2 nodes per thread
    float gv[2];
    #pragma unroll
    for (int p = 0; p < 2; ++p) {
        const float4* row = (const float4*)(hb + (size_t)(tid + p*256)*HF);
        float s = 0.f;
        #pragma unroll 8
        for (int c = 0; c < 64; ++c) {
            float4 a = row[c];
            float4 w = *(const float4*)&gw[c*4];
            s += a.x*w.x + a.y*w.y + a.z*w.z + a.w*w.w;
        }
        s += gate_b[0];
        gv[p] = fmaxf(s, 0.f);
    }

    // softmax over 512 gates
    float m = fmaxf(gv[0], gv[1]);
    #pragma unroll
    for (int o = 32; o > 0; o >>= 1) m = fmaxf(m, __shfl_xor(m, o, 64));
    if ((tid & 63) == 0) red[tid >> 6] = m;
    __syncthreads();
    m = fmaxf(fmaxf(red[0], red[1]), fmaxf(red[2], red[3]));
    float e0 = expf(gv[0] - m), e1 = expf(gv[1] - m);
    float S = blk_sum256(e0 + e1, red);
    attn[tid]       = e0 / S;
    attn[tid + 256] = e1 / S;
    __syncthreads();

    // gemb[f] = sum_n attn[n] * h3[n][f]   (f = tid, coalesced)
    float acc = 0.f;
    #pragma unroll 4
    for (int n = 0; n < NND; ++n)
        acc = fmaf(attn[n], hb[(size_t)n*HF + tid], acc);
    gemb[tid] = acc;
    __syncthreads();

    // affinity = gemb @ aff_w + aff_b
    float sa = blk_sum256(acc * aff_w[tid], red);
    if (tid == 0) out[g] = sa + aff_b[0];

    // pose = relu(gemb @ rl_w1 + rl_b1) @ rl_w2 + rl_b2
    float t = rl_b1[tid];
    #pragma unroll 4
    for (int k2 = 0; k2 < HF; ++k2)
        t = fmaf(gemb[k2], rl_w1[(size_t)k2*HF + tid], t);
    t = fmaxf(t, 0.f);
    float s0 = blk_sum256(t * rl_w2[(size_t)tid*3 + 0], red);
    if (tid == 0) out[128 + g*3 + 0] = s0 + rl_b2[0];
    float s1 = blk_sum256(t * rl_w2[(size_t)tid*3 + 1], red);
    if (tid == 0) out[128 + g*3 + 1] = s1 + rl_b2[1];
    float s2 = blk_sum256(t * rl_w2[(size_t)tid*3 + 2], red);
    if (tid == 0) out[128 + g*3 + 2] = s2 + rl_b2[2];
}

// ---------------------------------------------------------------------------
extern "C" void kernel_launch(void* const* d_in, const int* in_sizes, int n_in,
                              void* d_out, int out_size, void* d_ws, size_t ws_size,
                              hipStream_t stream)
{
    const float* x      = (const float*)d_in[0];
    const float* pos    = (const float*)d_in[1];
    const float* W1     = (const float*)d_in[2];
    const float* b1     = (const float*)d_in[3];
    const float* W2     = (const float*)d_in[4];
    const float* b2     = (const float*)d_in[5];
    const float* W3     = (const float*)d_in[6];
    const float* b3     = (const float*)d_in[7];
    const float* g1     = (const float*)d_in[8];
    const float* be1    = (const float*)d_in[9];
    const float* m1     = (const float*)d_in[10];
    const float* v1     = (const float*)d_in[11];
    const float* g2     = (const float*)d_in[12];
    const float* be2    = (const float*)d_in[13];
    const float* m2     = (const float*)d_in[14];
    const float* v2     = (const float*)d_in[15];
    const float* g3     = (const float*)d_in[16];
    const float* be3    = (const float*)d_in[17];
    const float* m3     = (const float*)d_in[18];
    const float* v3     = (const float*)d_in[19];
    const float* gate_w = (const float*)d_in[20];
    const float* gate_b = (const float*)d_in[21];
    const float* aff_w  = (const float*)d_in[22];
    const float* aff_b  = (const float*)d_in[23];
    const float* rl_w1  = (const float*)d_in[24];
    const float* rl_b1  = (const float*)d_in[25];
    const float* rl_w2  = (const float*)d_in[26];
    const float* rl_b2  = (const float*)d_in[27];
    float* out = (float*)d_out;

    char* wsb = (char*)d_ws;
    int*   nbr = (int*)wsb;                                   // NB_TOT*6 ints
    float* P1  = (float*)(wsb + (size_t)NB_TOT*KNN*4);        // 67.1 MB pool
    float* P2  = P1 + (size_t)NB_TOT*HF;                      // 67.1 MB pool

    knn_kernel<<<NBG*4, 256, 0, stream>>>(pos, nbr);
    // ha0 = agg(concat(x,pos))  [NB,132]
    agg_first<<<(NB_TOT*33)/256, 256, 0, stream>>>(x, pos, nbr, P1);
    // h1 = relu(bn1(ha0 @ W1 + b1))
    gemm_bn_relu<<<NB_TOT/64, 256, 0, stream>>>(P1, 132, 131, W1, b1, g1, be1, m1, v1, P2);
    // ha1 = agg(h1)
    agg_h<<<(NB_TOT*64)/256, 256, 0, stream>>>(P2, nbr, P1);
    // h2 = relu(bn2(ha1 @ W2 + b2))
    gemm_bn_relu<<<NB_TOT/64, 256, 0, stream>>>(P1, 256, 256, W2, b2, g2, be2, m2, v2, P2);
    // ha2 = agg(h2)
    agg_h<<<(NB_TOT*64)/256, 256, 0, stream>>>(P2, nbr, P1);
    // h3 = relu(bn3(ha2 @ W3 + b3))
    gemm_bn_relu<<<NB_TOT/64, 256, 0, stream>>>(P1, 256, 256, W3, b3, g3, be3, m3, v3, P2);
    // readout
    readout_kernel<<<NBG, 256, 0, stream>>>(P2, gate_w, gate_b, aff_w, aff_b,
                                            rl_w1, rl_b1, rl_w2, rl_b2, out);
}

// Round 3
// 379.229 us; speedup vs baseline: 2.0802x; 1.6135x over previous
//
#include <hip/hip_runtime.h>
#include <hip/hip_bf16.h>
#include <math.h>
#include <float.h>

#define NBG 128      // graphs
#define NND 512      // nodes per graph
#define KNN 6
#define NB_TOT (NBG*NND)
#define HF 256
#define NSTEP1 5     // layer-1 K padded to 160 (131 real)

typedef short bf16x8 __attribute__((ext_vector_type(8)));
typedef float f32x4 __attribute__((ext_vector_type(4)));

// byte offset of element (row, kbyte) in an 8-KB [128 rows][32 k] bf16 plane,
// XOR-swizzled so 16-lane frag reads cover all eight 16-B slots (2-way free).
__device__ __forceinline__ int swzoff(int row, int kbyte) {
    return (row*64 + kbyte) ^ (((row>>1)&3)<<4);
}

__device__ __forceinline__ void split_store(const float* v, char* hi_p, char* lo_p) {
    bf16x8 hi, lo;
    #pragma unroll
    for (int j = 0; j < 8; ++j) {
        __hip_bfloat16 h = __float2bfloat16(v[j]);
        float hf = __bfloat162float(h);
        __hip_bfloat16 l = __float2bfloat16(v[j] - hf);
        hi[j] = *(short*)&h;
        lo[j] = *(short*)&l;
    }
    *(bf16x8*)hi_p = hi;
    *(bf16x8*)lo_p = lo;
}

// ---------------------------------------------------------------------------
// kNN: 4 blocks/graph, 2 threads/node, register top-6 + pair merge.
// Writes LOCAL neighbor ids as ushort.
// ---------------------------------------------------------------------------
__global__ __launch_bounds__(256) void knn_kernel(const float* __restrict__ pos,
                                                  unsigned short* __restrict__ nbr)
{
    const int blk = blockIdx.x;           // 512 blocks
    const int g = blk >> 2;
    const int chunk = (blk & 3) * 128;
    const int tid = threadIdx.x;
    const int node = chunk + (tid >> 1);
    const int sub = tid & 1;

    __shared__ float4 p4[NND];            // (x, y, z, |p|^2)
    const float* pg = pos + (size_t)g * NND * 3;
    for (int n = tid; n < NND; n += 256) {
        float x = pg[n*3+0], y = pg[n*3+1], z = pg[n*3+2];
        p4[n] = make_float4(x, y, z, x*x + y*y + z*z);
    }
    __syncthreads();

    const float4 pi = p4[node];
    float bd[KNN]; int bi[KNN];
    #pragma unroll
    for (int q = 0; q < KNN; ++q) { bd[q] = FLT_MAX; bi[q] = 0x7fffffff; }

    const int j0 = sub * 256;
    for (int j = j0; j < j0 + 256; ++j) {
        float4 pj = p4[j];
        float d2 = pi.w + pj.w - 2.0f*(pi.x*pj.x + pi.y*pj.y + pi.z*pj.z);
        if (j != node && d2 < bd[KNN-1]) {
            float vd = d2; int vi = j;
            #pragma unroll
            for (int q = 0; q < KNN; ++q) {
                if (vd < bd[q]) {
                    float td = bd[q]; int ti = bi[q];
                    bd[q] = vd; bi[q] = vi; vd = td; vi = ti;
                }
            }
        }
    }

    float od[KNN]; int oi[KNN];
    #pragma unroll
    for (int q = 0; q < KNN; ++q) {
        od[q] = __shfl_xor(bd[q], 1);
        oi[q] = __shfl_xor(bi[q], 1);
    }
    float ld[KNN]; int li[KNN];
    #pragma unroll
    for (int q = 0; q < KNN; ++q) {
        float ad = bd[q], xd = od[KNN-1-q];
        int   ai = bi[q], xi = oi[KNN-1-q];
        bool t = (ad < xd) || (ad == xd && ai < xi);
        ld[q] = t ? ad : xd;
        li[q] = t ? ai : xi;
    }
    #define CE(a,b) { \
        bool sw = (ld[b] < ld[a]) || (ld[b] == ld[a] && li[b] < li[a]); \
        float td = sw ? ld[b] : ld[a]; float ud = sw ? ld[a] : ld[b];   \
        int   ti = sw ? li[b] : li[a]; int   ui = sw ? li[a] : li[b];   \
        ld[a] = td; li[a] = ti; ld[b] = ud; li[b] = ui; }
    CE(0,1) CE(1,2) CE(2,3) CE(3,4) CE(4,5)
    CE(0,1) CE(1,2) CE(2,3) CE(3,4)
    CE(0,1) CE(1,2) CE(2,3)
    CE(0,1) CE(1,2)
    CE(0,1)
    #undef CE

    if (sub == 0) {
        int base = (g*NND + node)*KNN;
        #pragma unroll
        for (int q = 0; q < KNN; ++q) nbr[base+q] = (unsigned short)li[q];
    }
}

// ---------------------------------------------------------------------------
// W pre-pass: build swizzled hi/lo bf16 LDS images of W.
// Layout: [nblk(2)][step][hi 8KB | lo 8KB]; plane element (col_local, kk).
// One thread per (nblk, step, col, 8k-chunk): 8 strided reads, 2x 16-B writes.
// ---------------------------------------------------------------------------
__global__ __launch_bounds__(256) void prew_kernel(const float* __restrict__ W,
                                                   int K, int nstep,
                                                   char* __restrict__ Wimg)
{
    int gid = blockIdx.x*256 + threadIdx.x;       // 2*nstep*512 threads
    int per_nb = nstep*512;
    int nb = gid / per_nb;
    int r  = gid - nb*per_nb;
    int step = r >> 9;
    int r2 = r & 511;
    int cl = r2 >> 2;
    int kc = (r2 & 3) * 8;
    float v[8];
    #pragma unroll
    for (int j = 0; j < 8; ++j) {
        int gk = step*32 + kc + j;
        v[j] = (gk < K) ? W[(size_t)gk*256 + nb*128 + cl] : 0.f;
    }
    char* base = Wimg + (size_t)nb*nstep*16384 + (size_t)step*16384;
    int off = swzoff(cl, kc*2);
    split_store(v, base + off, base + 8192 + off);
}

// ---------------------------------------------------------------------------
// agg_first: A1 image from concat(x,pos). One thread per (node, 8-feature
// chunk); 20 chunks/node (features 0..159; 131..159 zero).
// ---------------------------------------------------------------------------
__global__ __launch_bounds__(256) void agg_first(const float* __restrict__ x,
                                                 const float* __restrict__ pos,
                                                 const unsigned short* __restrict__ nbr,
                                                 char* __restrict__ Aimg)
{
    int gid = blockIdx.x*256 + threadIdx.x;   // NB_TOT*20
    int i = gid / 20, ch = gid - i*20;
    const float rs = 1.0f/sqrtf(7.0f);
    const float c1 = rs*rs, c2 = 1.0f/7.0f;
    const int gbase = i & ~(NND-1);
    float v[8];
    if (ch < 16) {
        int jn[KNN];
        #pragma unroll
        for (int q = 0; q < KNN; ++q) jn[q] = gbase + nbr[i*KNN+q];
        const float4* x4 = (const float4*)x;
        int c4 = ch*2;
        float4 s0 = x4[(size_t)i*32 + c4], s1 = x4[(size_t)i*32 + c4 + 1];
        float a0=0,a1=0,a2=0,a3=0,b0=0,b1=0,b2=0,b3=0;
        #pragma unroll
        for (int q = 0; q < KNN; ++q) {
            float4 t0 = x4[(size_t)jn[q]*32 + c4];
            float4 t1 = x4[(size_t)jn[q]*32 + c4 + 1];
            a0+=t0.x; a1+=t0.y; a2+=t0.z; a3+=t0.w;
            b0+=t1.x; b1+=t1.y; b2+=t1.z; b3+=t1.w;
        }
        v[0]=a0*c1+s0.x*c2; v[1]=a1*c1+s0.y*c2; v[2]=a2*c1+s0.z*c2; v[3]=a3*c1+s0.w*c2;
        v[4]=b0*c1+s1.x*c2; v[5]=b1*c1+s1.y*c2; v[6]=b2*c1+s1.z*c2; v[7]=b3*c1+s1.w*c2;
    } else if (ch == 16) {
        int jn[KNN];
        #pragma unroll
        for (int q = 0; q < KNN; ++q) jn[q] = gbase + nbr[i*KNN+q];
        float ax=0, ay=0, az=0;
        #pragma unroll
        for (int q = 0; q < KNN; ++q) {
            ax += pos[(size_t)jn[q]*3+0];
            ay += pos[(size_t)jn[q]*3+1];
            az += pos[(size_t)jn[q]*3+2];
        }
        v[0] = ax*c1 + pos[(size_t)i*3+0]*c2;
        v[1] = ay*c1 + pos[(size_t)i*3+1]*c2;
        v[2] = az*c1 + pos[(size_t)i*3+2]*c2;
        v[3]=v[4]=v[5]=v[6]=v[7]=0.f;
    } else {
        #pragma unroll
        for (int j = 0; j < 8; ++j) v[j] = 0.f;
    }
    int mb = i >> 7, row = i & 127, step = ch >> 2, kbyte = (ch & 3)*16;
    char* base = Aimg + (size_t)mb*(NSTEP1*16384) + (size_t)step*16384;
    int off = swzoff(row, kbyte);
    split_store(v, base + off, base + 8192 + off);
}

// ---------------------------------------------------------------------------
// agg_h: A image from 256-dim h. One thread per (node, 8-feature chunk).
// ---------------------------------------------------------------------------
__global__ __launch_bounds__(256) void agg_h(const float* __restrict__ h,
                                             const unsigned short* __restrict__ nbr,
                                             char* __restrict__ Aimg)
{
    int gid = blockIdx.x*256 + threadIdx.x;   // NB_TOT*32
    int i = gid >> 5, ch = gid & 31;
    const float rs = 1.0f/sqrtf(7.0f);
    const float c1 = rs*rs, c2 = 1.0f/7.0f;
    const int gbase = i & ~(NND-1);
    int jn[KNN];
    #pragma unroll
    for (int q = 0; q < KNN; ++q) jn[q] = gbase + nbr[i*KNN+q];
    const float4* h4 = (const float4*)h;
    int c4 = ch*2;
    float4 s0 = h4[(size_t)i*64 + c4], s1 = h4[(size_t)i*64 + c4 + 1];
    float a0=0,a1=0,a2=0,a3=0,b0=0,b1=0,b2=0,b3=0;
    #pragma unroll
    for (int q = 0; q < KNN; ++q) {
        float4 t0 = h4[(size_t)jn[q]*64 + c4];
        float4 t1 = h4[(size_t)jn[q]*64 + c4 + 1];
        a0+=t0.x; a1+=t0.y; a2+=t0.z; a3+=t0.w;
        b0+=t1.x; b1+=t1.y; b2+=t1.z; b3+=t1.w;
    }
    float v[8];
    v[0]=a0*c1+s0.x*c2; v[1]=a1*c1+s0.y*c2; v[2]=a2*c1+s0.z*c2; v[3]=a3*c1+s0.w*c2;
    v[4]=b0*c1+s1.x*c2; v[5]=b1*c1+s1.y*c2; v[6]=b2*c1+s1.z*c2; v[7]=b3*c1+s1.w*c2;
    int mb = i >> 7, row = i & 127, step = ch >> 2, kbyte = (ch & 3)*16;
    char* base = Aimg + (size_t)mb*(8*16384) + (size_t)step*16384;
    int off = swzoff(row, kbyte);
    split_store(v, base + off, base + 8192 + off);
}

// ---------------------------------------------------------------------------
// MFMA GEMM: C[128x128 tile] = bn_relu(A @ W). bf16 2-split, 3 passes.
// 256 threads = 4 waves (2m x 2n), wave tile 64x64 = 4x4 frags 16x16x32.
// Staging via global_load_lds(16B) from pre-swizzled images.
// ---------------------------------------------------------------------------
__global__ __launch_bounds__(256,4) void gemm_mfma(
    const char* __restrict__ Aimg, const char* __restrict__ Wimg, int nstep,
    const float* __restrict__ bias,
    const float* __restrict__ gam, const float* __restrict__ bet,
    const float* __restrict__ mu,  const float* __restrict__ var,
    float* __restrict__ out)
{
    __shared__ uint4 lds4[34816/16];
    char* lds  = (char*)lds4;
    char* Alds = lds;
    char* Wlds = lds + 16384;
    float* scs = (float*)(lds + 32768);
    float* shs = scs + 256;
    const int tid = threadIdx.x;
    const int lane = tid & 63, wave = tid >> 6;
    const int wm = wave >> 1, wn = wave & 1;
    const int mblk = blockIdx.x, nblk = blockIdx.y;

    if (tid < 256) {
        float s = gam[tid] / sqrtf(var[tid] + 1e-5f);
        scs[tid] = s;
        shs[tid] = bet[tid] + (bias[tid] - mu[tid]) * s;
    }

    const char* Ab = Aimg + (size_t)mblk * nstep * 16384;
    const char* Wb = Wimg + (size_t)nblk * nstep * 16384;

    // per-wave staging assignment: waves 0,1 -> A (16 KB), waves 2,3 -> W
    const char* gbase; char* lbase;
    int soff;
    if (wave < 2) { gbase = Ab;  lbase = Alds; soff = wave*8192; }
    else          { gbase = Wb;  lbase = Wlds; soff = (wave-2)*8192; }

    f32x4 acc[4][4];
    #pragma unroll
    for (int m = 0; m < 4; ++m)
        #pragma unroll
        for (int n = 0; n < 4; ++n) acc[m][n] = (f32x4){0.f,0.f,0.f,0.f};

    for (int s = 0; s < nstep; ++s) {
        #pragma unroll
        for (int i = 0; i < 8; ++i) {
            int off = soff + i*1024;
            __builtin_amdgcn_global_load_lds(
                (const __attribute__((address_space(1))) void*)(gbase + (size_t)s*16384 + off + lane*16),
                (__attribute__((address_space(3))) void*)(lbase + off), 16, 0, 0);
        }
        __syncthreads();
        const int kb = (lane >> 4) * 16;
        bf16x8 ah[4], al[4];
        #pragma unroll
        for (int m = 0; m < 4; ++m) {
            int row = wm*64 + m*16 + (lane & 15);
            int off = swzoff(row, kb);
            ah[m] = *(const bf16x8*)(Alds + off);
            al[m] = *(const bf16x8*)(Alds + 8192 + off);
        }
        #pragma unroll
        for (int n = 0; n < 4; ++n) {
            int col = wn*64 + n*16 + (lane & 15);
            int off = swzoff(col, kb);
            bf16x8 bh = *(const bf16x8*)(Wlds + off);
            bf16x8 bl = *(const bf16x8*)(Wlds + 8192 + off);
            #pragma unroll
            for (int m = 0; m < 4; ++m) {
                acc[m][n] = __builtin_amdgcn_mfma_f32_16x16x32_bf16(ah[m], bh, acc[m][n], 0, 0, 0);
                acc[m][n] = __builtin_amdgcn_mfma_f32_16x16x32_bf16(al[m], bh, acc[m][n], 0, 0, 0);
                acc[m][n] = __builtin_amdgcn_mfma_f32_16x16x32_bf16(ah[m], bl, acc[m][n], 0, 0, 0);
            }
        }
        __syncthreads();
    }

    // epilogue: bn+relu, scalar dword stores (64-B coalesced per 16-lane group)
    #pragma unroll
    for (int n = 0; n < 4; ++n) {
        int c = nblk*128 + wn*64 + n*16 + (lane & 15);
        float sc = scs[c], sh = shs[c];
        #pragma unroll
        for (int m = 0; m < 4; ++m) {
            int r0 = mblk*128 + wm*64 + m*16 + (lane >> 4)*4;
            #pragma unroll
            for (int q = 0; q < 4; ++q) {
                float v = acc[m][n][q]*sc + sh;
                out[(size_t)(r0+q)*256 + c] = fmaxf(v, 0.f);
            }
        }
    }
}

// ---------------------------------------------------------------------------
// Readout: per-graph gate -> softmax -> weighted sum -> heads.
// ---------------------------------------------------------------------------
__device__ __forceinline__ float blk_sum256(float v, volatile float* red)
{
    #pragma unroll
    for (int o = 32; o > 0; o >>= 1) v += __shfl_xor(v, o, 64);
    __syncthreads();
    if ((threadIdx.x & 63) == 0) red[threadIdx.x >> 6] = v;
    __syncthreads();
    return (red[0] + red[1]) + (red[2] + red[3]);
}

__global__ __launch_bounds__(256) void readout_kernel(
    const float* __restrict__ h3,
    const float* __restrict__ gate_w, const float* __restrict__ gate_b,
    const float* __restrict__ aff_w,  const float* __restrict__ aff_b,
    const float* __restrict__ rl_w1,  const float* __restrict__ rl_b1,
    const float* __restrict__ rl_w2,  const float* __restrict__ rl_b2,
    float* __restrict__ out)
{
    int g = blockIdx.x, tid = threadIdx.x;
    __shared__ float attn[NND];
    __shared__ float gemb[HF];
    __shared__ float gw[HF];
    __shared__ float red[4];

    gw[tid] = gate_w[tid];
    __syncthreads();
    const float* hb = h3 + (size_t)g * NND * HF;

    float gv[2];
    #pragma unroll
    for (int p = 0; p < 2; ++p) {
        const float4* row = (const float4*)(hb + (size_t)(tid + p*256)*HF);
        float s = 0.f;
        #pragma unroll 8
        for (int c = 0; c < 64; ++c) {
            float4 a = row[c];
            float4 w = *(const float4*)&gw[c*4];
            s += a.x*w.x + a.y*w.y + a.z*w.z + a.w*w.w;
        }
        s += gate_b[0];
        gv[p] = fmaxf(s, 0.f);
    }

    float m = fmaxf(gv[0], gv[1]);
    #pragma unroll
    for (int o = 32; o > 0; o >>= 1) m = fmaxf(m, __shfl_xor(m, o, 64));
    if ((tid & 63) == 0) red[tid >> 6] = m;
    __syncthreads();
    m = fmaxf(fmaxf(red[0], red[1]), fmaxf(red[2], red[3]));
    float e0 = expf(gv[0] - m), e1 = expf(gv[1] - m);
    float S = blk_sum256(e0 + e1, red);
    attn[tid]       = e0 / S;
    attn[tid + 256] = e1 / S;
    __syncthreads();

    float acc = 0.f;
    #pragma unroll 4
    for (int n = 0; n < NND; ++n)
        acc = fmaf(attn[n], hb[(size_t)n*HF + tid], acc);
    gemb[tid] = acc;
    __syncthreads();

    float sa = blk_sum256(acc * aff_w[tid], red);
    if (tid == 0) out[g] = sa + aff_b[0];

    float t = rl_b1[tid];
    #pragma unroll 4
    for (int k2 = 0; k2 < HF; ++k2)
        t = fmaf(gemb[k2], rl_w1[(size_t)k2*HF + tid], t);
    t = fmaxf(t, 0.f);
    float s0 = blk_sum256(t * rl_w2[(size_t)tid*3 + 0], red);
    if (tid == 0) out[128 + g*3 + 0] = s0 + rl_b2[0];
    float s1 = blk_sum256(t * rl_w2[(size_t)tid*3 + 1], red);
    if (tid == 0) out[128 + g*3 + 1] = s1 + rl_b2[1];
    float s2 = blk_sum256(t * rl_w2[(size_t)tid*3 + 2], red);
    if (tid == 0) out[128 + g*3 + 2] = s2 + rl_b2[2];
}

// ---------------------------------------------------------------------------
extern "C" void kernel_launch(void* const* d_in, const int* in_sizes, int n_in,
                              void* d_out, int out_size, void* d_ws, size_t ws_size,
                              hipStream_t stream)
{
    const float* x      = (const float*)d_in[0];
    const float* pos    = (const float*)d_in[1];
    const float* W1     = (const float*)d_in[2];
    const float* b1     = (const float*)d_in[3];
    const float* W2     = (const float*)d_in[4];
    const float* b2     = (const float*)d_in[5];
    const float* W3     = (const float*)d_in[6];
    const float* b3     = (const float*)d_in[7];
    const float* g1     = (const float*)d_in[8];
    const float* be1    = (const float*)d_in[9];
    const float* m1     = (const float*)d_in[10];
    const float* v1     = (const float*)d_in[11];
    const float* g2     = (const float*)d_in[12];
    const float* be2    = (const float*)d_in[13];
    const float* m2     = (const float*)d_in[14];
    const float* v2     = (const float*)d_in[15];
    const float* g3     = (const float*)d_in[16];
    const float* be3    = (const float*)d_in[17];
    const float* m3     = (const float*)d_in[18];
    const float* v3     = (const float*)d_in[19];
    const float* gate_w = (const float*)d_in[20];
    const float* gate_b = (const float*)d_in[21];
    const float* aff_w  = (const float*)d_in[22];
    const float* aff_b  = (const float*)d_in[23];
    const float* rl_w1  = (const float*)d_in[24];
    const float* rl_b1  = (const float*)d_in[25];
    const float* rl_w2  = (const float*)d_in[26];
    const float* rl_b2  = (const float*)d_in[27];
    float* out = (float*)d_out;

    // workspace layout (total ~135.7 MB, < proven 135.8 MB extent)
    char* wsb = (char*)d_ws;
    unsigned short* nbr = (unsigned short*)wsb;               // 786,432 B
    char* Wimg1 = wsb + 786432;                               // 163,840 B
    char* Wimg2 = Wimg1 + (size_t)2*NSTEP1*16384;             // 262,144 B
    char* Wimg3 = Wimg2 + (size_t)2*8*16384;                  // 262,144 B
    float* h    = (float*)(Wimg3 + (size_t)2*8*16384);        // 67.1 MB
    char* Aimg  = (char*)(h + (size_t)NB_TOT*HF);             // 67.1 MB

    knn_kernel<<<NBG*4, 256, 0, stream>>>(pos, nbr);
    prew_kernel<<<(2*NSTEP1*512)/256, 256, 0, stream>>>(W1, 131, NSTEP1, Wimg1);
    prew_kernel<<<(2*8*512)/256, 256, 0, stream>>>(W2, 256, 8, Wimg2);
    prew_kernel<<<(2*8*512)/256, 256, 0, stream>>>(W3, 256, 8, Wimg3);

    agg_first<<<(NB_TOT*20)/256, 256, 0, stream>>>(x, pos, nbr, Aimg);
    gemm_mfma<<<dim3(NB_TOT/128, 2), 256, 0, stream>>>(Aimg, Wimg1, NSTEP1,
        b1, g1, be1, m1, v1, h);
    agg_h<<<(NB_TOT*32)/256, 256, 0, stream>>>(h, nbr, Aimg);
    gemm_mfma<<<dim3(NB_TOT/128, 2), 256, 0, stream>>>(Aimg, Wimg2, 8,
        b2, g2, be2, m2, v2, h);
    agg_h<<<(NB_TOT*32)/256, 256, 0, stream>>>(h, nbr, Aimg);
    gemm_mfma<<<dim3(NB_TOT/128, 2), 256, 0, stream>>>(Aimg, Wimg3, 8,
        b3, g3, be3, m3, v3, h);
    readout_kernel<<<NBG, 256, 0, stream>>>(h, gate_w, gate_b, aff_w, aff_b,
                                            rl_w1, rl_b1, rl_w2, rl_b2, out);
}

// Round 4
// 375.977 us; speedup vs baseline: 2.0982x; 1.0086x over previous
//
#include <hip/hip_runtime.h>
#include <hip/hip_bf16.h>
#include <math.h>
#include <float.h>

#define NBG 128      // graphs
#define NND 512      // nodes per graph
#define KNN 6
#define NB_TOT (NBG*NND)
#define HF 256
#define NSTEP1 5     // layer-1 K padded to 160 (131 real)

typedef short bf16x8 __attribute__((ext_vector_type(8)));
typedef float f32x4 __attribute__((ext_vector_type(4)));

// byte offset of element (row, kbyte) in an 8-KB [128 rows][32 k] bf16 plane,
// XOR-swizzled so 16-lane frag reads cover all eight 16-B slots (2-way free).
__device__ __forceinline__ int swzoff(int row, int kbyte) {
    return (row*64 + kbyte) ^ (((row>>1)&3)<<4);
}

__device__ __forceinline__ void split_store(const float* v, char* hi_p, char* lo_p) {
    bf16x8 hi, lo;
    #pragma unroll
    for (int j = 0; j < 8; ++j) {
        __hip_bfloat16 h = __float2bfloat16(v[j]);
        float hf = __bfloat162float(h);
        __hip_bfloat16 l = __float2bfloat16(v[j] - hf);
        hi[j] = *(short*)&h;
        lo[j] = *(short*)&l;
    }
    *(bf16x8*)hi_p = hi;
    *(bf16x8*)lo_p = lo;
}

// ---------------------------------------------------------------------------
// kNN v3: 8 blocks/graph (1024 blocks), 4 threads per node, 128 candidates
// each. LDS candidate array padded (+1 float4 per 64) so the 4 per-wave
// sub-addresses hit disjoint bank groups (conflict-free broadcast).
// Merge: shfl_xor 1 then 2, min-trick + sorting network.
// Total order (d2 asc, idx asc) matches jax.lax.top_k tie semantics.
// ---------------------------------------------------------------------------
__global__ __launch_bounds__(256) void knn_kernel(const float* __restrict__ pos,
                                                  unsigned short* __restrict__ nbr)
{
    const int blk = blockIdx.x;           // 1024 blocks
    const int g = blk >> 3;
    const int chunk = (blk & 7) * 64;
    const int tid = threadIdx.x;
    const int node = chunk + (tid >> 2);  // local node id
    const int sub = tid & 3;

    __shared__ float4 p4[NND + (NND>>6)]; // padded: idx j -> j + (j>>6)
    const float* pg = pos + (size_t)g * NND * 3;
    for (int n = tid; n < NND; n += 256) {
        float x = pg[n*3+0], y = pg[n*3+1], z = pg[n*3+2];
        p4[n + (n>>6)] = make_float4(x, y, z, x*x + y*y + z*z);
    }
    __syncthreads();

    const float4 pi = p4[node + (node>>6)];
    const float m2x = -2.0f*pi.x, m2y = -2.0f*pi.y, m2z = -2.0f*pi.z;
    float bd[KNN]; int bi[KNN];
    #pragma unroll
    for (int q = 0; q < KNN; ++q) { bd[q] = FLT_MAX; bi[q] = 0x7fffffff; }

    const int j0 = sub * 128;
    #pragma unroll 4
    for (int j = j0; j < j0 + 128; ++j) {
        float4 pj = p4[j + (j>>6)];
        float d2 = pi.w + pj.w + m2x*pj.x + m2y*pj.y + m2z*pj.z;
        d2 = (j == node) ? FLT_MAX : d2;
        if (d2 < bd[KNN-1]) {
            float vd = d2; int vi = j;
            #pragma unroll
            for (int q = 0; q < KNN; ++q) {
                if (vd < bd[q]) {
                    float td = bd[q]; int ti = bi[q];
                    bd[q] = vd; bi[q] = vi; vd = td; vi = ti;
                }
            }
        }
    }

    #define CE(a,b) { \
        bool sw = (ld[b] < ld[a]) || (ld[b] == ld[a] && li[b] < li[a]); \
        float td = sw ? ld[b] : ld[a]; float ud = sw ? ld[a] : ld[b];   \
        int   ti = sw ? li[b] : li[a]; int   ui = sw ? li[a] : li[b];   \
        ld[a] = td; li[a] = ti; ld[b] = ud; li[b] = ui; }
    #define MERGE(mask) { \
        float od[KNN]; int oi[KNN]; \
        _Pragma("unroll") \
        for (int q = 0; q < KNN; ++q) { \
            od[q] = __shfl_xor(ld[q], mask); \
            oi[q] = __shfl_xor(li[q], mask); \
        } \
        _Pragma("unroll") \
        for (int q = 0; q < KNN; ++q) { \
            float ad = ld[q], xd = od[KNN-1-q]; \
            int   ai = li[q], xi = oi[KNN-1-q]; \
            bool t = (ad < xd) || (ad == xd && ai < xi); \
            ld[q] = t ? ad : xd; \
            li[q] = t ? ai : xi; \
        } \
        CE(0,1) CE(1,2) CE(2,3) CE(3,4) CE(4,5) \
        CE(0,1) CE(1,2) CE(2,3) CE(3,4) \
        CE(0,1) CE(1,2) CE(2,3) \
        CE(0,1) CE(1,2) \
        CE(0,1) }

    float ld[KNN]; int li[KNN];
    #pragma unroll
    for (int q = 0; q < KNN; ++q) { ld[q] = bd[q]; li[q] = bi[q]; }
    MERGE(1)
    MERGE(2)
    #undef MERGE
    #undef CE

    if (sub == 0) {
        int base = (g*NND + node)*KNN;
        #pragma unroll
        for (int q = 0; q < KNN; ++q) nbr[base+q] = (unsigned short)li[q];
    }
}

// ---------------------------------------------------------------------------
// W pre-pass: build swizzled hi/lo bf16 LDS images of W.
// Layout: [nblk(2)][step][hi 8KB | lo 8KB]; plane element (col_local, kk).
// ---------------------------------------------------------------------------
__global__ __launch_bounds__(256) void prew_kernel(const float* __restrict__ W,
                                                   int K, int nstep,
                                                   char* __restrict__ Wimg)
{
    int gid = blockIdx.x*256 + threadIdx.x;       // 2*nstep*512 threads
    int per_nb = nstep*512;
    int nb = gid / per_nb;
    int r  = gid - nb*per_nb;
    int step = r >> 9;
    int r2 = r & 511;
    int cl = r2 >> 2;
    int kc = (r2 & 3) * 8;
    float v[8];
    #pragma unroll
    for (int j = 0; j < 8; ++j) {
        int gk = step*32 + kc + j;
        v[j] = (gk < K) ? W[(size_t)gk*256 + nb*128 + cl] : 0.f;
    }
    char* base = Wimg + (size_t)nb*nstep*16384 + (size_t)step*16384;
    int off = swzoff(cl, kc*2);
    split_store(v, base + off, base + 8192 + off);
}

// ---------------------------------------------------------------------------
// agg_first: A1 image from concat(x,pos). One thread per (node, 8-feature
// chunk); 20 chunks/node (features 0..159; 131..159 zero).
// ---------------------------------------------------------------------------
__global__ __launch_bounds__(256) void agg_first(const float* __restrict__ x,
                                                 const float* __restrict__ pos,
                                                 const unsigned short* __restrict__ nbr,
                                                 char* __restrict__ Aimg)
{
    int gid = blockIdx.x*256 + threadIdx.x;   // NB_TOT*20
    int i = gid / 20, ch = gid - i*20;
    const float rs = 1.0f/sqrtf(7.0f);
    const float c1 = rs*rs, c2 = 1.0f/7.0f;
    const int gbase = i & ~(NND-1);
    float v[8];
    if (ch < 16) {
        int jn[KNN];
        #pragma unroll
        for (int q = 0; q < KNN; ++q) jn[q] = gbase + nbr[i*KNN+q];
        const float4* x4 = (const float4*)x;
        int c4 = ch*2;
        float4 s0 = x4[(size_t)i*32 + c4], s1 = x4[(size_t)i*32 + c4 + 1];
        float a0=0,a1=0,a2=0,a3=0,b0=0,b1=0,b2=0,b3=0;
        #pragma unroll
        for (int q = 0; q < KNN; ++q) {
            float4 t0 = x4[(size_t)jn[q]*32 + c4];
            float4 t1 = x4[(size_t)jn[q]*32 + c4 + 1];
            a0+=t0.x; a1+=t0.y; a2+=t0.z; a3+=t0.w;
            b0+=t1.x; b1+=t1.y; b2+=t1.z; b3+=t1.w;
        }
        v[0]=a0*c1+s0.x*c2; v[1]=a1*c1+s0.y*c2; v[2]=a2*c1+s0.z*c2; v[3]=a3*c1+s0.w*c2;
        v[4]=b0*c1+s1.x*c2; v[5]=b1*c1+s1.y*c2; v[6]=b2*c1+s1.z*c2; v[7]=b3*c1+s1.w*c2;
    } else if (ch == 16) {
        int jn[KNN];
        #pragma unroll
        for (int q = 0; q < KNN; ++q) jn[q] = gbase + nbr[i*KNN+q];
        float ax=0, ay=0, az=0;
        #pragma unroll
        for (int q = 0; q < KNN; ++q) {
            ax += pos[(size_t)jn[q]*3+0];
            ay += pos[(size_t)jn[q]*3+1];
            az += pos[(size_t)jn[q]*3+2];
        }
        v[0] = ax*c1 + pos[(size_t)i*3+0]*c2;
        v[1] = ay*c1 + pos[(size_t)i*3+1]*c2;
        v[2] = az*c1 + pos[(size_t)i*3+2]*c2;
        v[3]=v[4]=v[5]=v[6]=v[7]=0.f;
    } else {
        #pragma unroll
        for (int j = 0; j < 8; ++j) v[j] = 0.f;
    }
    int mb = i >> 7, row = i & 127, step = ch >> 2, kbyte = (ch & 3)*16;
    char* base = Aimg + (size_t)mb*(NSTEP1*16384) + (size_t)step*16384;
    int off = swzoff(row, kbyte);
    split_store(v, base + off, base + 8192 + off);
}

// ---------------------------------------------------------------------------
// agg_h: A image from 256-dim h. One thread per (node, 8-feature chunk).
// ---------------------------------------------------------------------------
__global__ __launch_bounds__(256) void agg_h(const float* __restrict__ h,
                                             const unsigned short* __restrict__ nbr,
                                             char* __restrict__ Aimg)
{
    int gid = blockIdx.x*256 + threadIdx.x;   // NB_TOT*32
    int i = gid >> 5, ch = gid & 31;
    const float rs = 1.0f/sqrtf(7.0f);
    const float c1 = rs*rs, c2 = 1.0f/7.0f;
    const int gbase = i & ~(NND-1);
    int jn[KNN];
    #pragma unroll
    for (int q = 0; q < KNN; ++q) jn[q] = gbase + nbr[i*KNN+q];
    const float4* h4 = (const float4*)h;
    int c4 = ch*2;
    float4 s0 = h4[(size_t)i*64 + c4], s1 = h4[(size_t)i*64 + c4 + 1];
    float a0=0,a1=0,a2=0,a3=0,b0=0,b1=0,b2=0,b3=0;
    #pragma unroll
    for (int q = 0; q < KNN; ++q) {
        float4 t0 = h4[(size_t)jn[q]*64 + c4];
        float4 t1 = h4[(size_t)jn[q]*64 + c4 + 1];
        a0+=t0.x; a1+=t0.y; a2+=t0.z; a3+=t0.w;
        b0+=t1.x; b1+=t1.y; b2+=t1.z; b3+=t1.w;
    }
    float v[8];
    v[0]=a0*c1+s0.x*c2; v[1]=a1*c1+s0.y*c2; v[2]=a2*c1+s0.z*c2; v[3]=a3*c1+s0.w*c2;
    v[4]=b0*c1+s1.x*c2; v[5]=b1*c1+s1.y*c2; v[6]=b2*c1+s1.z*c2; v[7]=b3*c1+s1.w*c2;
    int mb = i >> 7, row = i & 127, step = ch >> 2, kbyte = (ch & 3)*16;
    char* base = Aimg + (size_t)mb*(8*16384) + (size_t)step*16384;
    int off = swzoff(row, kbyte);
    split_store(v, base + off, base + 8192 + off);
}

// ---------------------------------------------------------------------------
// MFMA GEMM: C[128x128 tile] = bn_relu(A @ W). bf16 2-split, 3 passes.
// ---------------------------------------------------------------------------
__global__ __launch_bounds__(256,4) void gemm_mfma(
    const char* __restrict__ Aimg, const char* __restrict__ Wimg, int nstep,
    const float* __restrict__ bias,
    const float* __restrict__ gam, const float* __restrict__ bet,
    const float* __restrict__ mu,  const float* __restrict__ var,
    float* __restrict__ out)
{
    __shared__ uint4 lds4[34816/16];
    char* lds  = (char*)lds4;
    char* Alds = lds;
    char* Wlds = lds + 16384;
    float* scs = (float*)(lds + 32768);
    float* shs = scs + 256;
    const int tid = threadIdx.x;
    const int lane = tid & 63, wave = tid >> 6;
    const int wm = wave >> 1, wn = wave & 1;
    const int mblk = blockIdx.x, nblk = blockIdx.y;

    if (tid < 256) {
        float s = gam[tid] / sqrtf(var[tid] + 1e-5f);
        scs[tid] = s;
        shs[tid] = bet[tid] + (bias[tid] - mu[tid]) * s;
    }

    const char* Ab = Aimg + (size_t)mblk * nstep * 16384;
    const char* Wb = Wimg + (size_t)nblk * nstep * 16384;

    const char* gbase; char* lbase;
    int soff;
    if (wave < 2) { gbase = Ab;  lbase = Alds; soff = wave*8192; }
    else          { gbase = Wb;  lbase = Wlds; soff = (wave-2)*8192; }

    f32x4 acc[4][4];
    #pragma unroll
    for (int m = 0; m < 4; ++m)
        #pragma unroll
        for (int n = 0; n < 4; ++n) acc[m][n] = (f32x4){0.f,0.f,0.f,0.f};

    for (int s = 0; s < nstep; ++s) {
        #pragma unroll
        for (int i = 0; i < 8; ++i) {
            int off = soff + i*1024;
            __builtin_amdgcn_global_load_lds(
                (const __attribute__((address_space(1))) void*)(gbase + (size_t)s*16384 + off + lane*16),
                (__attribute__((address_space(3))) void*)(lbase + off), 16, 0, 0);
        }
        __syncthreads();
        const int kb = (lane >> 4) * 16;
        bf16x8 ah[4], al[4];
        #pragma unroll
        for (int m = 0; m < 4; ++m) {
            int row = wm*64 + m*16 + (lane & 15);
            int off = swzoff(row, kb);
            ah[m] = *(const bf16x8*)(Alds + off);
            al[m] = *(const bf16x8*)(Alds + 8192 + off);
        }
        #pragma unroll
        for (int n = 0; n < 4; ++n) {
            int col = wn*64 + n*16 + (lane & 15);
            int off = swzoff(col, kb);
            bf16x8 bh = *(const bf16x8*)(Wlds + off);
            bf16x8 bl = *(const bf16x8*)(Wlds + 8192 + off);
            #pragma unroll
            for (int m = 0; m < 4; ++m) {
                acc[m][n] = __builtin_amdgcn_mfma_f32_16x16x32_bf16(ah[m], bh, acc[m][n], 0, 0, 0);
                acc[m][n] = __builtin_amdgcn_mfma_f32_16x16x32_bf16(al[m], bh, acc[m][n], 0, 0, 0);
                acc[m][n] = __builtin_amdgcn_mfma_f32_16x16x32_bf16(ah[m], bl, acc[m][n], 0, 0, 0);
            }
        }
        __syncthreads();
    }

    #pragma unroll
    for (int n = 0; n < 4; ++n) {
        int c = nblk*128 + wn*64 + n*16 + (lane & 15);
        float sc = scs[c], sh = shs[c];
        #pragma unroll
        for (int m = 0; m < 4; ++m) {
            int r0 = mblk*128 + wm*64 + m*16 + (lane >> 4)*4;
            #pragma unroll
            for (int q = 0; q < 4; ++q) {
                float v = acc[m][n][q]*sc + sh;
                out[(size_t)(r0+q)*256 + c] = fmaxf(v, 0.f);
            }
        }
    }
}

// ---------------------------------------------------------------------------
// Readout: per-graph gate -> softmax -> weighted sum -> heads.
// ---------------------------------------------------------------------------
__device__ __forceinline__ float blk_sum256(float v, volatile float* red)
{
    #pragma unroll
    for (int o = 32; o > 0; o >>= 1) v += __shfl_xor(v, o, 64);
    __syncthreads();
    if ((threadIdx.x & 63) == 0) red[threadIdx.x >> 6] = v;
    __syncthreads();
    return (red[0] + red[1]) + (red[2] + red[3]);
}

__global__ __launch_bounds__(256) void readout_kernel(
    const float* __restrict__ h3,
    const float* __restrict__ gate_w, const float* __restrict__ gate_b,
    const float* __restrict__ aff_w,  const float* __restrict__ aff_b,
    const float* __restrict__ rl_w1,  const float* __restrict__ rl_b1,
    const float* __restrict__ rl_w2,  const float* __restrict__ rl_b2,
    float* __restrict__ out)
{
    int g = blockIdx.x, tid = threadIdx.x;
    __shared__ float attn[NND];
    __shared__ float gemb[HF];
    __shared__ float gw[HF];
    __shared__ float red[4];

    gw[tid] = gate_w[tid];
    __syncthreads();
    const float* hb = h3 + (size_t)g * NND * HF;

    float gv[2];
    #pragma unroll
    for (int p = 0; p < 2; ++p) {
        const float4* row = (const float4*)(hb + (size_t)(tid + p*256)*HF);
        float s = 0.f;
        #pragma unroll 8
        for (int c = 0; c < 64; ++c) {
            float4 a = row[c];
            float4 w = *(const float4*)&gw[c*4];
            s += a.x*w.x + a.y*w.y + a.z*w.z + a.w*w.w;
        }
        s += gate_b[0];
        gv[p] = fmaxf(s, 0.f);
    }

    float m = fmaxf(gv[0], gv[1]);
    #pragma unroll
    for (int o = 32; o > 0; o >>= 1) m = fmaxf(m, __shfl_xor(m, o, 64));
    if ((tid & 63) == 0) red[tid >> 6] = m;
    __syncthreads();
    m = fmaxf(fmaxf(red[0], red[1]), fmaxf(red[2], red[3]));
    float e0 = expf(gv[0] - m), e1 = expf(gv[1] - m);
    float S = blk_sum256(e0 + e1, red);
    attn[tid]       = e0 / S;
    attn[tid + 256] = e1 / S;
    __syncthreads();

    float acc = 0.f;
    #pragma unroll 4
    for (int n = 0; n < NND; ++n)
        acc = fmaf(attn[n], hb[(size_t)n*HF + tid], acc);
    gemb[tid] = acc;
    __syncthreads();

    float sa = blk_sum256(acc * aff_w[tid], red);
    if (tid == 0) out[g] = sa + aff_b[0];

    float t = rl_b1[tid];
    #pragma unroll 4
    for (int k2 = 0; k2 < HF; ++k2)
        t = fmaf(gemb[k2], rl_w1[(size_t)k2*HF + tid], t);
    t = fmaxf(t, 0.f);
    float s0 = blk_sum256(t * rl_w2[(size_t)tid*3 + 0], red);
    if (tid == 0) out[128 + g*3 + 0] = s0 + rl_b2[0];
    float s1 = blk_sum256(t * rl_w2[(size_t)tid*3 + 1], red);
    if (tid == 0) out[128 + g*3 + 1] = s1 + rl_b2[1];
    float s2 = blk_sum256(t * rl_w2[(size_t)tid*3 + 2], red);
    if (tid == 0) out[128 + g*3 + 2] = s2 + rl_b2[2];
}

// ---------------------------------------------------------------------------
extern "C" void kernel_launch(void* const* d_in, const int* in_sizes, int n_in,
                              void* d_out, int out_size, void* d_ws, size_t ws_size,
                              hipStream_t stream)
{
    const float* x      = (const float*)d_in[0];
    const float* pos    = (const float*)d_in[1];
    const float* W1     = (const float*)d_in[2];
    const float* b1     = (const float*)d_in[3];
    const float* W2     = (const float*)d_in[4];
    const float* b2     = (const float*)d_in[5];
    const float* W3     = (const float*)d_in[6];
    const float* b3     = (const float*)d_in[7];
    const float* g1     = (const float*)d_in[8];
    const float* be1    = (const float*)d_in[9];
    const float* m1     = (const float*)d_in[10];
    const float* v1     = (const float*)d_in[11];
    const float* g2     = (const float*)d_in[12];
    const float* be2    = (const float*)d_in[13];
    const float* m2     = (const float*)d_in[14];
    const float* v2     = (const float*)d_in[15];
    const float* g3     = (const float*)d_in[16];
    const float* be3    = (const float*)d_in[17];
    const float* m3     = (const float*)d_in[18];
    const float* v3     = (const float*)d_in[19];
    const float* gate_w = (const float*)d_in[20];
    const float* gate_b = (const float*)d_in[21];
    const float* aff_w  = (const float*)d_in[22];
    const float* aff_b  = (const float*)d_in[23];
    const float* rl_w1  = (const float*)d_in[24];
    const float* rl_b1  = (const float*)d_in[25];
    const float* rl_w2  = (const float*)d_in[26];
    const float* rl_b2  = (const float*)d_in[27];
    float* out = (float*)d_out;

    // workspace layout (total ~135.7 MB)
    char* wsb = (char*)d_ws;
    unsigned short* nbr = (unsigned short*)wsb;               // 786,432 B
    char* Wimg1 = wsb + 786432;                               // 163,840 B
    char* Wimg2 = Wimg1 + (size_t)2*NSTEP1*16384;             // 262,144 B
    char* Wimg3 = Wimg2 + (size_t)2*8*16384;                  // 262,144 B
    float* h    = (float*)(Wimg3 + (size_t)2*8*16384);        // 67.1 MB
    char* Aimg  = (char*)(h + (size_t)NB_TOT*HF);             // 67.1 MB

    knn_kernel<<<NBG*8, 256, 0, stream>>>(pos, nbr);
    prew_kernel<<<(2*NSTEP1*512)/256, 256, 0, stream>>>(W1, 131, NSTEP1, Wimg1);
    prew_kernel<<<(2*8*512)/256, 256, 0, stream>>>(W2, 256, 8, Wimg2);
    prew_kernel<<<(2*8*512)/256, 256, 0, stream>>>(W3, 256, 8, Wimg3);

    agg_first<<<(NB_TOT*20)/256, 256, 0, stream>>>(x, pos, nbr, Aimg);
    gemm_mfma<<<dim3(NB_TOT/128, 2), 256, 0, stream>>>(Aimg, Wimg1, NSTEP1,
        b1, g1, be1, m1, v1, h);
    agg_h<<<(NB_TOT*32)/256, 256, 0, stream>>>(h, nbr, Aimg);
    gemm_mfma<<<dim3(NB_TOT/128, 2), 256, 0, stream>>>(Aimg, Wimg2, 8,
        b2, g2, be2, m2, v2, h);
    agg_h<<<(NB_TOT*32)/256, 256, 0, stream>>>(h, nbr, Aimg);
    gemm_mfma<<<dim3(NB_TOT/128, 2), 256, 0, stream>>>(Aimg, Wimg3, 8,
        b3, g3, be3, m3, v3, h);
    readout_kernel<<<NBG, 256, 0, stream>>>(h, gate_w, gate_b, aff_w, aff_b,
                                            rl_w1, rl_b1, rl_w2, rl_b2, out);
}

// Round 6
// 336.483 us; speedup vs baseline: 2.3445x; 1.1174x over previous
//
#include <hip/hip_runtime.h>
#include <hip/hip_bf16.h>
#include <math.h>
#include <float.h>

#define NBG 128      // graphs
#define NND 512      // nodes per graph
#define KNN 6
#define NB_TOT (NBG*NND)
#define HF 256
#define NSTEP1 5     // layer-1 K padded to 160 (131 real)

typedef short bf16x8 __attribute__((ext_vector_type(8)));
typedef float f32x4 __attribute__((ext_vector_type(4)));

// byte offset of element (row, kbyte) in an 8-KB [128 rows][32 k] bf16 plane,
// XOR-swizzled so 16-lane frag reads cover all eight 16-B slots (2-way free).
__device__ __forceinline__ int swzoff(int row, int kbyte) {
    return (row*64 + kbyte) ^ (((row>>1)&3)<<4);
}

__device__ __forceinline__ void split_store(const float* v, char* hi_p, char* lo_p) {
    bf16x8 hi, lo;
    #pragma unroll
    for (int j = 0; j < 8; ++j) {
        __hip_bfloat16 h = __float2bfloat16(v[j]);
        float hf = __bfloat162float(h);
        __hip_bfloat16 l = __float2bfloat16(v[j] - hf);
        hi[j] = *(short*)&h;
        lo[j] = *(short*)&l;
    }
    *(bf16x8*)hi_p = hi;
    *(bf16x8*)lo_p = lo;
}

// ---------------------------------------------------------------------------
// kNN v4b: 8 blocks/graph, 4 lanes/node (128 candidates each), branchless
// (d2,idx) carry-chain insertion, two independent chains per lane (ILP).
// Reduced unroll + looped merges to keep compile time sane.
// Strict '<' on the j-ascending stream keeps lower-index-wins tie semantics;
// cross-merges use full (d2, idx) lex compare.
// ---------------------------------------------------------------------------
__global__ __launch_bounds__(256) void knn_kernel(const float* __restrict__ pos,
                                                  unsigned short* __restrict__ nbr)
{
    const int blk = blockIdx.x;           // 1024 blocks
    const int g = blk >> 3;
    const int chunk = (blk & 7) * 64;
    const int tid = threadIdx.x;
    const int node = chunk + (tid >> 2);  // local node id
    const int sub = tid & 3;

    __shared__ float4 p4[NND + (NND>>6)]; // padded: idx j -> j + (j>>6)
    const float* pg = pos + (size_t)g * NND * 3;
    for (int n = tid; n < NND; n += 256) {
        float x = pg[n*3+0], y = pg[n*3+1], z = pg[n*3+2];
        p4[n + (n>>6)] = make_float4(x, y, z, x*x + y*y + z*z);
    }
    __syncthreads();

    const float4 pi = p4[node + (node>>6)];
    const float m2x = -2.0f*pi.x, m2y = -2.0f*pi.y, m2z = -2.0f*pi.z;

    float bdA[KNN], bdB[KNN]; int biA[KNN], biB[KNN];
    #pragma unroll
    for (int q = 0; q < KNN; ++q) {
        bdA[q] = FLT_MAX; biA[q] = 0x7fffffff;
        bdB[q] = FLT_MAX; biB[q] = 0x7fffffff;
    }

    const int j0 = sub * 128;
    // j in [j0, j0+64): j>>6 == sub*2; j in [j0+64, j0+128): j>>6 == sub*2+1
    const float4* baseA = &p4[sub*130];
    const float4* baseB = &p4[sub*130 + 65];

    #pragma unroll 2
    for (int t = 0; t < 64; ++t) {
        int ja = j0 + t, jb = j0 + 64 + t;
        float4 pa = baseA[t];
        float4 pb = baseB[t];
        float da = fmaf(m2z, pa.z, fmaf(m2y, pa.y, fmaf(m2x, pa.x, pa.w)));
        float db = fmaf(m2z, pb.z, fmaf(m2y, pb.y, fmaf(m2x, pb.x, pb.w)));
        da = (ja == node) ? FLT_MAX : da;
        db = (jb == node) ? FLT_MAX : db;
        // branchless carry-chain insert (strict <: incumbents win ties)
        float ca = da; int ia = ja;
        float cb = db; int ib = jb;
        #pragma unroll
        for (int q = 0; q < KNN; ++q) {
            bool sa = ca < bdA[q];
            float t1 = sa ? ca : bdA[q]; float t2 = sa ? bdA[q] : ca;
            int   t3 = sa ? ia : biA[q]; int   t4 = sa ? biA[q] : ia;
            bdA[q] = t1; ca = t2; biA[q] = t3; ia = t4;
            bool sb = cb < bdB[q];
            float u1 = sb ? cb : bdB[q]; float u2 = sb ? bdB[q] : cb;
            int   u3 = sb ? ib : biB[q]; int   u4 = sb ? biB[q] : ib;
            bdB[q] = u1; cb = u2; biB[q] = u3; ib = u4;
        }
    }

    // local merge of chains A and B (min-trick + bubble sort network)
    float ld[KNN]; int li[KNN];
    #pragma unroll
    for (int q = 0; q < KNN; ++q) {
        float ad = bdA[q], xd = bdB[KNN-1-q];
        int   ai = biA[q], xi = biB[KNN-1-q];
        bool t = (ad < xd) || (ad == xd && ai < xi);
        ld[q] = t ? ad : xd;
        li[q] = t ? ai : xi;
    }
    #pragma unroll
    for (int pass = 0; pass < KNN-1; ++pass)
        #pragma unroll
        for (int a = 0; a < KNN-1-pass; ++a) {
            int b = a+1;
            bool sw = (ld[b] < ld[a]) || (ld[b] == ld[a] && li[b] < li[a]);
            float td = sw ? ld[b] : ld[a]; float ud = sw ? ld[a] : ld[b];
            int   ti = sw ? li[b] : li[a]; int   ui = sw ? li[a] : li[b];
            ld[a] = td; li[a] = ti; ld[b] = ud; li[b] = ui;
        }

    // cross-lane merges: partner masks 1 then 2 (within wave)
    #pragma unroll
    for (int mi = 0; mi < 2; ++mi) {
        const int mask = 1 << mi;
        float od[KNN]; int oi[KNN];
        #pragma unroll
        for (int q = 0; q < KNN; ++q) {
            od[q] = __shfl_xor(ld[q], mask);
            oi[q] = __shfl_xor(li[q], mask);
        }
        #pragma unroll
        for (int q = 0; q < KNN; ++q) {
            float ad = ld[q], xd = od[KNN-1-q];
            int   ai = li[q], xi = oi[KNN-1-q];
            bool t = (ad < xd) || (ad == xd && ai < xi);
            ld[q] = t ? ad : xd;
            li[q] = t ? ai : xi;
        }
        #pragma unroll
        for (int pass = 0; pass < KNN-1; ++pass)
            #pragma unroll
            for (int a = 0; a < KNN-1-pass; ++a) {
                int b = a+1;
                bool sw = (ld[b] < ld[a]) || (ld[b] == ld[a] && li[b] < li[a]);
                float td = sw ? ld[b] : ld[a]; float ud = sw ? ld[a] : ld[b];
                int   ti = sw ? li[b] : li[a]; int   ui = sw ? li[a] : li[b];
                ld[a] = td; li[a] = ti; ld[b] = ud; li[b] = ui;
            }
    }

    if (sub == 0) {
        int base = (g*NND + node)*KNN;
        #pragma unroll
        for (int q = 0; q < KNN; ++q) nbr[base+q] = (unsigned short)li[q];
    }
}

// ---------------------------------------------------------------------------
// W pre-pass: build swizzled hi/lo bf16 LDS images of W.
// Layout: [nblk(2)][step][hi 8KB | lo 8KB]; plane element (col_local, kk).
// ---------------------------------------------------------------------------
__global__ __launch_bounds__(256) void prew_kernel(const float* __restrict__ W,
                                                   int K, int nstep,
                                                   char* __restrict__ Wimg)
{
    int gid = blockIdx.x*256 + threadIdx.x;       // 2*nstep*512 threads
    int per_nb = nstep*512;
    int nb = gid / per_nb;
    int r  = gid - nb*per_nb;
    int step = r >> 9;
    int r2 = r & 511;
    int cl = r2 >> 2;
    int kc = (r2 & 3) * 8;
    float v[8];
    #pragma unroll
    for (int j = 0; j < 8; ++j) {
        int gk = step*32 + kc + j;
        v[j] = (gk < K) ? W[(size_t)gk*256 + nb*128 + cl] : 0.f;
    }
    char* base = Wimg + (size_t)nb*nstep*16384 + (size_t)step*16384;
    int off = swzoff(cl, kc*2);
    split_store(v, base + off, base + 8192 + off);
}

// ---------------------------------------------------------------------------
// agg_first: A1 image from concat(x,pos). One thread per (node, 8-feature
// chunk); 20 chunks/node (features 0..159; 131..159 zero).
// ---------------------------------------------------------------------------
__global__ __launch_bounds__(256) void agg_first(const float* __restrict__ x,
                                                 const float* __restrict__ pos,
                                                 const unsigned short* __restrict__ nbr,
                                                 char* __restrict__ Aimg)
{
    int gid = blockIdx.x*256 + threadIdx.x;   // NB_TOT*20
    int i = gid / 20, ch = gid - i*20;
    const float rs = 1.0f/sqrtf(7.0f);
    const float c1 = rs*rs, c2 = 1.0f/7.0f;
    const int gbase = i & ~(NND-1);
    float v[8];
    if (ch < 16) {
        int jn[KNN];
        #pragma unroll
        for (int q = 0; q < KNN; ++q) jn[q] = gbase + nbr[i*KNN+q];
        const float4* x4 = (const float4*)x;
        int c4 = ch*2;
        float4 s0 = x4[(size_t)i*32 + c4], s1 = x4[(size_t)i*32 + c4 + 1];
        float a0=0,a1=0,a2=0,a3=0,b0=0,b1=0,b2=0,b3=0;
        #pragma unroll
        for (int q = 0; q < KNN; ++q) {
            float4 t0 = x4[(size_t)jn[q]*32 + c4];
            float4 t1 = x4[(size_t)jn[q]*32 + c4 + 1];
            a0+=t0.x; a1+=t0.y; a2+=t0.z; a3+=t0.w;
            b0+=t1.x; b1+=t1.y; b2+=t1.z; b3+=t1.w;
        }
        v[0]=a0*c1+s0.x*c2; v[1]=a1*c1+s0.y*c2; v[2]=a2*c1+s0.z*c2; v[3]=a3*c1+s0.w*c2;
        v[4]=b0*c1+s1.x*c2; v[5]=b1*c1+s1.y*c2; v[6]=b2*c1+s1.z*c2; v[7]=b3*c1+s1.w*c2;
    } else if (ch == 16) {
        int jn[KNN];
        #pragma unroll
        for (int q = 0; q < KNN; ++q) jn[q] = gbase + nbr[i*KNN+q];
        float ax=0, ay=0, az=0;
        #pragma unroll
        for (int q = 0; q < KNN; ++q) {
            ax += pos[(size_t)jn[q]*3+0];
            ay += pos[(size_t)jn[q]*3+1];
            az += pos[(size_t)jn[q]*3+2];
        }
        v[0] = ax*c1 + pos[(size_t)i*3+0]*c2;
        v[1] = ay*c1 + pos[(size_t)i*3+1]*c2;
        v[2] = az*c1 + pos[(size_t)i*3+2]*c2;
        v[3]=v[4]=v[5]=v[6]=v[7]=0.f;
    } else {
        #pragma unroll
        for (int j = 0; j < 8; ++j) v[j] = 0.f;
    }
    int mb = i >> 7, row = i & 127, step = ch >> 2, kbyte = (ch & 3)*16;
    char* base = Aimg + (size_t)mb*(NSTEP1*16384) + (size_t)step*16384;
    int off = swzoff(row, kbyte);
    split_store(v, base + off, base + 8192 + off);
}

// ---------------------------------------------------------------------------
// agg_h: A image from 256-dim h. One thread per (node, 8-feature chunk).
// ---------------------------------------------------------------------------
__global__ __launch_bounds__(256) void agg_h(const float* __restrict__ h,
                                             const unsigned short* __restrict__ nbr,
                                             char* __restrict__ Aimg)
{
    int gid = blockIdx.x*256 + threadIdx.x;   // NB_TOT*32
    int i = gid >> 5, ch = gid & 31;
    const float rs = 1.0f/sqrtf(7.0f);
    const float c1 = rs*rs, c2 = 1.0f/7.0f;
    const int gbase = i & ~(NND-1);
    int jn[KNN];
    #pragma unroll
    for (int q = 0; q < KNN; ++q) jn[q] = gbase + nbr[i*KNN+q];
    const float4* h4 = (const float4*)h;
    int c4 = ch*2;
    float4 s0 = h4[(size_t)i*64 + c4], s1 = h4[(size_t)i*64 + c4 + 1];
    float a0=0,a1=0,a2=0,a3=0,b0=0,b1=0,b2=0,b3=0;
    #pragma unroll
    for (int q = 0; q < KNN; ++q) {
        float4 t0 = h4[(size_t)jn[q]*64 + c4];
        float4 t1 = h4[(size_t)jn[q]*64 + c4 + 1];
        a0+=t0.x; a1+=t0.y; a2+=t0.z; a3+=t0.w;
        b0+=t1.x; b1+=t1.y; b2+=t1.z; b3+=t1.w;
    }
    float v[8];
    v[0]=a0*c1+s0.x*c2; v[1]=a1*c1+s0.y*c2; v[2]=a2*c1+s0.z*c2; v[3]=a3*c1+s0.w*c2;
    v[4]=b0*c1+s1.x*c2; v[5]=b1*c1+s1.y*c2; v[6]=b2*c1+s1.z*c2; v[7]=b3*c1+s1.w*c2;
    int mb = i >> 7, row = i & 127, step = ch >> 2, kbyte = (ch & 3)*16;
    char* base = Aimg + (size_t)mb*(8*16384) + (size_t)step*16384;
    int off = swzoff(row, kbyte);
    split_store(v, base + off, base + 8192 + off);
}

// ---------------------------------------------------------------------------
// MFMA GEMM: C[128x128 tile] = bn_relu(A @ W). bf16 2-split, 3 passes.
// ---------------------------------------------------------------------------
__global__ __launch_bounds__(256,4) void gemm_mfma(
    const char* __restrict__ Aimg, const char* __restrict__ Wimg, int nstep,
    const float* __restrict__ bias,
    const float* __restrict__ gam, const float* __restrict__ bet,
    const float* __restrict__ mu,  const float* __restrict__ var,
    float* __restrict__ out)
{
    __shared__ uint4 lds4[34816/16];
    char* lds  = (char*)lds4;
    char* Alds = lds;
    char* Wlds = lds + 16384;
    float* scs = (float*)(lds + 32768);
    float* shs = scs + 256;
    const int tid = threadIdx.x;
    const int lane = tid & 63, wave = tid >> 6;
    const int wm = wave >> 1, wn = wave & 1;
    const int mblk = blockIdx.x, nblk = blockIdx.y;

    if (tid < 256) {
        float s = gam[tid] / sqrtf(var[tid] + 1e-5f);
        scs[tid] = s;
        shs[tid] = bet[tid] + (bias[tid] - mu[tid]) * s;
    }

    const char* Ab = Aimg + (size_t)mblk * nstep * 16384;
    const char* Wb = Wimg + (size_t)nblk * nstep * 16384;

    const char* gbase; char* lbase;
    int soff;
    if (wave < 2) { gbase = Ab;  lbase = Alds; soff = wave*8192; }
    else          { gbase = Wb;  lbase = Wlds; soff = (wave-2)*8192; }

    f32x4 acc[4][4];
    #pragma unroll
    for (int m = 0; m < 4; ++m)
        #pragma unroll
        for (int n = 0; n < 4; ++n) acc[m][n] = (f32x4){0.f,0.f,0.f,0.f};

    for (int s = 0; s < nstep; ++s) {
        #pragma unroll
        for (int i = 0; i < 8; ++i) {
            int off = soff + i*1024;
            __builtin_amdgcn_global_load_lds(
                (const __attribute__((address_space(1))) void*)(gbase + (size_t)s*16384 + off + lane*16),
                (__attribute__((address_space(3))) void*)(lbase + off), 16, 0, 0);
        }
        __syncthreads();
        const int kb = (lane >> 4) * 16;
        bf16x8 ah[4], al[4];
        #pragma unroll
        for (int m = 0; m < 4; ++m) {
            int row = wm*64 + m*16 + (lane & 15);
            int off = swzoff(row, kb);
            ah[m] = *(const bf16x8*)(Alds + off);
            al[m] = *(const bf16x8*)(Alds + 8192 + off);
        }
        #pragma unroll
        for (int n = 0; n < 4; ++n) {
            int col = wn*64 + n*16 + (lane & 15);
            int off = swzoff(col, kb);
            bf16x8 bh = *(const bf16x8*)(Wlds + off);
            bf16x8 bl = *(const bf16x8*)(Wlds + 8192 + off);
            #pragma unroll
            for (int m = 0; m < 4; ++m) {
                acc[m][n] = __builtin_amdgcn_mfma_f32_16x16x32_bf16(ah[m], bh, acc[m][n], 0, 0, 0);
                acc[m][n] = __builtin_amdgcn_mfma_f32_16x16x32_bf16(al[m], bh, acc[m][n], 0, 0, 0);
                acc[m][n] = __builtin_amdgcn_mfma_f32_16x16x32_bf16(ah[m], bl, acc[m][n], 0, 0, 0);
            }
        }
        __syncthreads();
    }

    #pragma unroll
    for (int n = 0; n < 4; ++n) {
        int c = nblk*128 + wn*64 + n*16 + (lane & 15);
        float sc = scs[c], sh = shs[c];
        #pragma unroll
        for (int m = 0; m < 4; ++m) {
            int r0 = mblk*128 + wm*64 + m*16 + (lane >> 4)*4;
            #pragma unroll
            for (int q = 0; q < 4; ++q) {
                float v = acc[m][n][q]*sc + sh;
                out[(size_t)(r0+q)*256 + c] = fmaxf(v, 0.f);
            }
        }
    }
}

// ---------------------------------------------------------------------------
// Readout: per-graph gate -> softmax -> weighted sum -> heads.
// ---------------------------------------------------------------------------
__device__ __forceinline__ float blk_sum256(float v, volatile float* red)
{
    #pragma unroll
    for (int o = 32; o > 0; o >>= 1) v += __shfl_xor(v, o, 64);
    __syncthreads();
    if ((threadIdx.x & 63) == 0) red[threadIdx.x >> 6] = v;
    __syncthreads();
    return (red[0] + red[1]) + (red[2] + red[3]);
}

__global__ __launch_bounds__(256) void readout_kernel(
    const float* __restrict__ h3,
    const float* __restrict__ gate_w, const float* __restrict__ gate_b,
    const float* __restrict__ aff_w,  const float* __restrict__ aff_b,
    const float* __restrict__ rl_w1,  const float* __restrict__ rl_b1,
    const float* __restrict__ rl_w2,  const float* __restrict__ rl_b2,
    float* __restrict__ out)
{
    int g = blockIdx.x, tid = threadIdx.x;
    __shared__ float attn[NND];
    __shared__ float gemb[HF];
    __shared__ float gw[HF];
    __shared__ float red[4];

    gw[tid] = gate_w[tid];
    __syncthreads();
    const float* hb = h3 + (size_t)g * NND * HF;

    float gv[2];
    #pragma unroll
    for (int p = 0; p < 2; ++p) {
        const float4* row = (const float4*)(hb + (size_t)(tid + p*256)*HF);
        float s = 0.f;
        #pragma unroll 8
        for (int c = 0; c < 64; ++c) {
            float4 a = row[c];
            float4 w = *(const float4*)&gw[c*4];
            s += a.x*w.x + a.y*w.y + a.z*w.z + a.w*w.w;
        }
        s += gate_b[0];
        gv[p] = fmaxf(s, 0.f);
    }

    float m = fmaxf(gv[0], gv[1]);
    #pragma unroll
    for (int o = 32; o > 0; o >>= 1) m = fmaxf(m, __shfl_xor(m, o, 64));
    if ((tid & 63) == 0) red[tid >> 6] = m;
    __syncthreads();
    m = fmaxf(fmaxf(red[0], red[1]), fmaxf(red[2], red[3]));
    float e0 = expf(gv[0] - m), e1 = expf(gv[1] - m);
    float S = blk_sum256(e0 + e1, red);
    attn[tid]       = e0 / S;
    attn[tid + 256] = e1 / S;
    __syncthreads();

    float acc = 0.f;
    #pragma unroll 4
    for (int n = 0; n < NND; ++n)
        acc = fmaf(attn[n], hb[(size_t)n*HF + tid], acc);
    gemb[tid] = acc;
    __syncthreads();

    float sa = blk_sum256(acc * aff_w[tid], red);
    if (tid == 0) out[g] = sa + aff_b[0];

    float t = rl_b1[tid];
    #pragma unroll 4
    for (int k2 = 0; k2 < HF; ++k2)
        t = fmaf(gemb[k2], rl_w1[(size_t)k2*HF + tid], t);
    t = fmaxf(t, 0.f);
    float s0 = blk_sum256(t * rl_w2[(size_t)tid*3 + 0], red);
    if (tid == 0) out[128 + g*3 + 0] = s0 + rl_b2[0];
    float s1 = blk_sum256(t * rl_w2[(size_t)tid*3 + 1], red);
    if (tid == 0) out[128 + g*3 + 1] = s1 + rl_b2[1];
    float s2 = blk_sum256(t * rl_w2[(size_t)tid*3 + 2], red);
    if (tid == 0) out[128 + g*3 + 2] = s2 + rl_b2[2];
}

// ---------------------------------------------------------------------------
extern "C" void kernel_launch(void* const* d_in, const int* in_sizes, int n_in,
                              void* d_out, int out_size, void* d_ws, size_t ws_size,
                              hipStream_t stream)
{
    const float* x      = (const float*)d_in[0];
    const float* pos    = (const float*)d_in[1];
    const float* W1     = (const float*)d_in[2];
    const float* b1     = (const float*)d_in[3];
    const float* W2     = (const float*)d_in[4];
    const float* b2     = (const float*)d_in[5];
    const float* W3     = (const float*)d_in[6];
    const float* b3     = (const float*)d_in[7];
    const float* g1     = (const float*)d_in[8];
    const float* be1    = (const float*)d_in[9];
    const float* m1     = (const float*)d_in[10];
    const float* v1     = (const float*)d_in[11];
    const float* g2     = (const float*)d_in[12];
    const float* be2    = (const float*)d_in[13];
    const float* m2     = (const float*)d_in[14];
    const float* v2     = (const float*)d_in[15];
    const float* g3     = (const float*)d_in[16];
    const float* be3    = (const float*)d_in[17];
    const float* m3     = (const float*)d_in[18];
    const float* v3     = (const float*)d_in[19];
    const float* gate_w = (const float*)d_in[20];
    const float* gate_b = (const float*)d_in[21];
    const float* aff_w  = (const float*)d_in[22];
    const float* aff_b  = (const float*)d_in[23];
    const float* rl_w1  = (const float*)d_in[24];
    const float* rl_b1  = (const float*)d_in[25];
    const float* rl_w2  = (const float*)d_in[26];
    const float* rl_b2  = (const float*)d_in[27];
    float* out = (float*)d_out;

    // workspace layout (total ~135.7 MB)
    char* wsb = (char*)d_ws;
    unsigned short* nbr = (unsigned short*)wsb;               // 786,432 B
    char* Wimg1 = wsb + 786432;                               // 163,840 B
    char* Wimg2 = Wimg1 + (size_t)2*NSTEP1*16384;             // 262,144 B
    char* Wimg3 = Wimg2 + (size_t)2*8*16384;                  // 262,144 B
    float* h    = (float*)(Wimg3 + (size_t)2*8*16384);        // 67.1 MB
    char* Aimg  = (char*)(h + (size_t)NB_TOT*HF);             // 67.1 MB

    knn_kernel<<<NBG*8, 256, 0, stream>>>(pos, nbr);
    prew_kernel<<<(2*NSTEP1*512)/256, 256, 0, stream>>>(W1, 131, NSTEP1, Wimg1);
    prew_kernel<<<(2*8*512)/256, 256, 0, stream>>>(W2, 256, 8, Wimg2);
    prew_kernel<<<(2*8*512)/256, 256, 0, stream>>>(W3, 256, 8, Wimg3);

    agg_first<<<(NB_TOT*20)/256, 256, 0, stream>>>(x, pos, nbr, Aimg);
    gemm_mfma<<<dim3(NB_TOT/128, 2), 256, 0, stream>>>(Aimg, Wimg1, NSTEP1,
        b1, g1, be1, m1, v1, h);
    agg_h<<<(NB_TOT*32)/256, 256, 0, stream>>>(h, nbr, Aimg);
    gemm_mfma<<<dim3(NB_TOT/128, 2), 256, 0, stream>>>(Aimg, Wimg2, 8,
        b2, g2, be2, m2, v2, h);
    agg_h<<<(NB_TOT*32)/256, 256, 0, stream>>>(h, nbr, Aimg);
    gemm_mfma<<<dim3(NB_TOT/128, 2), 256, 0, stream>>>(Aimg, Wimg3, 8,
        b3, g3, be3, m3, v3, h);
    readout_kernel<<<NBG, 256, 0, stream>>>(h, gate_w, gate_b, aff_w, aff_b,
                                            rl_w1, rl_b1, rl_w2, rl_b2, out);
}

// Round 7
// 312.067 us; speedup vs baseline: 2.5279x; 1.0782x over previous
//
#include <hip/hip_runtime.h>
#include <hip/hip_bf16.h>
#include <math.h>
#include <float.h>

#define NBG 128      // graphs
#define NND 512      // nodes per graph
#define KNN 6
#define NB_TOT (NBG*NND)
#define HF 256
#define NSTEP1 5     // layer-1 K padded to 160 (131 real)

typedef short bf16x8 __attribute__((ext_vector_type(8)));
typedef float f32x4 __attribute__((ext_vector_type(4)));

// byte offset of element (row, kbyte) in an 8-KB [128 rows][32 k] bf16 plane,
// XOR-swizzled so 16-lane frag reads cover all eight 16-B slots (2-way free).
__device__ __forceinline__ int swzoff(int row, int kbyte) {
    return (row*64 + kbyte) ^ (((row>>1)&3)<<4);
}

__device__ __forceinline__ void split_store(const float* v, char* hi_p, char* lo_p) {
    bf16x8 hi, lo;
    #pragma unroll
    for (int j = 0; j < 8; ++j) {
        __hip_bfloat16 h = __float2bfloat16(v[j]);
        float hf = __bfloat162float(h);
        __hip_bfloat16 l = __float2bfloat16(v[j] - hf);
        hi[j] = *(short*)&h;
        lo[j] = *(short*)&l;
    }
    *(bf16x8*)hi_p = hi;
    *(bf16x8*)lo_p = lo;
}

// ---------------------------------------------------------------------------
// kNN v4b: 8 blocks/graph, 4 lanes/node (128 candidates each), branchless
// (d2,idx) carry-chain insertion, two independent chains per lane (ILP).
// ---------------------------------------------------------------------------
__global__ __launch_bounds__(256) void knn_kernel(const float* __restrict__ pos,
                                                  unsigned short* __restrict__ nbr)
{
    const int blk = blockIdx.x;           // 1024 blocks
    const int g = blk >> 3;
    const int chunk = (blk & 7) * 64;
    const int tid = threadIdx.x;
    const int node = chunk + (tid >> 2);  // local node id
    const int sub = tid & 3;

    __shared__ float4 p4[NND + (NND>>6)]; // padded: idx j -> j + (j>>6)
    const float* pg = pos + (size_t)g * NND * 3;
    for (int n = tid; n < NND; n += 256) {
        float x = pg[n*3+0], y = pg[n*3+1], z = pg[n*3+2];
        p4[n + (n>>6)] = make_float4(x, y, z, x*x + y*y + z*z);
    }
    __syncthreads();

    const float4 pi = p4[node + (node>>6)];
    const float m2x = -2.0f*pi.x, m2y = -2.0f*pi.y, m2z = -2.0f*pi.z;

    float bdA[KNN], bdB[KNN]; int biA[KNN], biB[KNN];
    #pragma unroll
    for (int q = 0; q < KNN; ++q) {
        bdA[q] = FLT_MAX; biA[q] = 0x7fffffff;
        bdB[q] = FLT_MAX; biB[q] = 0x7fffffff;
    }

    const int j0 = sub * 128;
    const float4* baseA = &p4[sub*130];
    const float4* baseB = &p4[sub*130 + 65];

    #pragma unroll 2
    for (int t = 0; t < 64; ++t) {
        int ja = j0 + t, jb = j0 + 64 + t;
        float4 pa = baseA[t];
        float4 pb = baseB[t];
        float da = fmaf(m2z, pa.z, fmaf(m2y, pa.y, fmaf(m2x, pa.x, pa.w)));
        float db = fmaf(m2z, pb.z, fmaf(m2y, pb.y, fmaf(m2x, pb.x, pb.w)));
        da = (ja == node) ? FLT_MAX : da;
        db = (jb == node) ? FLT_MAX : db;
        float ca = da; int ia = ja;
        float cb = db; int ib = jb;
        #pragma unroll
        for (int q = 0; q < KNN; ++q) {
            bool sa = ca < bdA[q];
            float t1 = sa ? ca : bdA[q]; float t2 = sa ? bdA[q] : ca;
            int   t3 = sa ? ia : biA[q]; int   t4 = sa ? biA[q] : ia;
            bdA[q] = t1; ca = t2; biA[q] = t3; ia = t4;
            bool sb = cb < bdB[q];
            float u1 = sb ? cb : bdB[q]; float u2 = sb ? bdB[q] : cb;
            int   u3 = sb ? ib : biB[q]; int   u4 = sb ? biB[q] : ib;
            bdB[q] = u1; cb = u2; biB[q] = u3; ib = u4;
        }
    }

    float ld[KNN]; int li[KNN];
    #pragma unroll
    for (int q = 0; q < KNN; ++q) {
        float ad = bdA[q], xd = bdB[KNN-1-q];
        int   ai = biA[q], xi = biB[KNN-1-q];
        bool t = (ad < xd) || (ad == xd && ai < xi);
        ld[q] = t ? ad : xd;
        li[q] = t ? ai : xi;
    }
    #pragma unroll
    for (int pass = 0; pass < KNN-1; ++pass)
        #pragma unroll
        for (int a = 0; a < KNN-1-pass; ++a) {
            int b = a+1;
            bool sw = (ld[b] < ld[a]) || (ld[b] == ld[a] && li[b] < li[a]);
            float td = sw ? ld[b] : ld[a]; float ud = sw ? ld[a] : ld[b];
            int   ti = sw ? li[b] : li[a]; int   ui = sw ? li[a] : li[b];
            ld[a] = td; li[a] = ti; ld[b] = ud; li[b] = ui;
        }

    #pragma unroll
    for (int mi = 0; mi < 2; ++mi) {
        const int mask = 1 << mi;
        float od[KNN]; int oi[KNN];
        #pragma unroll
        for (int q = 0; q < KNN; ++q) {
            od[q] = __shfl_xor(ld[q], mask);
            oi[q] = __shfl_xor(li[q], mask);
        }
        #pragma unroll
        for (int q = 0; q < KNN; ++q) {
            float ad = ld[q], xd = od[KNN-1-q];
            int   ai = li[q], xi = oi[KNN-1-q];
            bool t = (ad < xd) || (ad == xd && ai < xi);
            ld[q] = t ? ad : xd;
            li[q] = t ? ai : xi;
        }
        #pragma unroll
        for (int pass = 0; pass < KNN-1; ++pass)
            #pragma unroll
            for (int a = 0; a < KNN-1-pass; ++a) {
                int b = a+1;
                bool sw = (ld[b] < ld[a]) || (ld[b] == ld[a] && li[b] < li[a]);
                float td = sw ? ld[b] : ld[a]; float ud = sw ? ld[a] : ld[b];
                int   ti = sw ? li[b] : li[a]; int   ui = sw ? li[a] : li[b];
                ld[a] = td; li[a] = ti; ld[b] = ud; li[b] = ui;
            }
    }

    if (sub == 0) {
        int base = (g*NND + node)*KNN;
        #pragma unroll
        for (int q = 0; q < KNN; ++q) nbr[base+q] = (unsigned short)li[q];
    }
}

// ---------------------------------------------------------------------------
// W pre-pass: build swizzled hi/lo bf16 LDS images of W.
// ---------------------------------------------------------------------------
__global__ __launch_bounds__(256) void prew_kernel(const float* __restrict__ W,
                                                   int K, int nstep,
                                                   char* __restrict__ Wimg)
{
    int gid = blockIdx.x*256 + threadIdx.x;       // 2*nstep*512 threads
    int per_nb = nstep*512;
    int nb = gid / per_nb;
    int r  = gid - nb*per_nb;
    int step = r >> 9;
    int r2 = r & 511;
    int cl = r2 >> 2;
    int kc = (r2 & 3) * 8;
    float v[8];
    #pragma unroll
    for (int j = 0; j < 8; ++j) {
        int gk = step*32 + kc + j;
        v[j] = (gk < K) ? W[(size_t)gk*256 + nb*128 + cl] : 0.f;
    }
    char* base = Wimg + (size_t)nb*nstep*16384 + (size_t)step*16384;
    int off = swzoff(cl, kc*2);
    split_store(v, base + off, base + 8192 + off);
}

// ---------------------------------------------------------------------------
// agg_first: A1 image from concat(x,pos).
// ---------------------------------------------------------------------------
__global__ __launch_bounds__(256) void agg_first(const float* __restrict__ x,
                                                 const float* __restrict__ pos,
                                                 const unsigned short* __restrict__ nbr,
                                                 char* __restrict__ Aimg)
{
    int gid = blockIdx.x*256 + threadIdx.x;   // NB_TOT*20
    int i = gid / 20, ch = gid - i*20;
    const float rs = 1.0f/sqrtf(7.0f);
    const float c1 = rs*rs, c2 = 1.0f/7.0f;
    const int gbase = i & ~(NND-1);
    float v[8];
    if (ch < 16) {
        int jn[KNN];
        #pragma unroll
        for (int q = 0; q < KNN; ++q) jn[q] = gbase + nbr[i*KNN+q];
        const float4* x4 = (const float4*)x;
        int c4 = ch*2;
        float4 s0 = x4[(size_t)i*32 + c4], s1 = x4[(size_t)i*32 + c4 + 1];
        float a0=0,a1=0,a2=0,a3=0,b0=0,b1=0,b2=0,b3=0;
        #pragma unroll
        for (int q = 0; q < KNN; ++q) {
            float4 t0 = x4[(size_t)jn[q]*32 + c4];
            float4 t1 = x4[(size_t)jn[q]*32 + c4 + 1];
            a0+=t0.x; a1+=t0.y; a2+=t0.z; a3+=t0.w;
            b0+=t1.x; b1+=t1.y; b2+=t1.z; b3+=t1.w;
        }
        v[0]=a0*c1+s0.x*c2; v[1]=a1*c1+s0.y*c2; v[2]=a2*c1+s0.z*c2; v[3]=a3*c1+s0.w*c2;
        v[4]=b0*c1+s1.x*c2; v[5]=b1*c1+s1.y*c2; v[6]=b2*c1+s1.z*c2; v[7]=b3*c1+s1.w*c2;
    } else if (ch == 16) {
        int jn[KNN];
        #pragma unroll
        for (int q = 0; q < KNN; ++q) jn[q] = gbase + nbr[i*KNN+q];
        float ax=0, ay=0, az=0;
        #pragma unroll
        for (int q = 0; q < KNN; ++q) {
            ax += pos[(size_t)jn[q]*3+0];
            ay += pos[(size_t)jn[q]*3+1];
            az += pos[(size_t)jn[q]*3+2];
        }
        v[0] = ax*c1 + pos[(size_t)i*3+0]*c2;
        v[1] = ay*c1 + pos[(size_t)i*3+1]*c2;
        v[2] = az*c1 + pos[(size_t)i*3+2]*c2;
        v[3]=v[4]=v[5]=v[6]=v[7]=0.f;
    } else {
        #pragma unroll
        for (int j = 0; j < 8; ++j) v[j] = 0.f;
    }
    int mb = i >> 7, row = i & 127, step = ch >> 2, kbyte = (ch & 3)*16;
    char* base = Aimg + (size_t)mb*(NSTEP1*16384) + (size_t)step*16384;
    int off = swzoff(row, kbyte);
    split_store(v, base + off, base + 8192 + off);
}

// ---------------------------------------------------------------------------
// agg_h: A image from 256-dim h.
// ---------------------------------------------------------------------------
__global__ __launch_bounds__(256) void agg_h(const float* __restrict__ h,
                                             const unsigned short* __restrict__ nbr,
                                             char* __restrict__ Aimg)
{
    int gid = blockIdx.x*256 + threadIdx.x;   // NB_TOT*32
    int i = gid >> 5, ch = gid & 31;
    const float rs = 1.0f/sqrtf(7.0f);
    const float c1 = rs*rs, c2 = 1.0f/7.0f;
    const int gbase = i & ~(NND-1);
    int jn[KNN];
    #pragma unroll
    for (int q = 0; q < KNN; ++q) jn[q] = gbase + nbr[i*KNN+q];
    const float4* h4 = (const float4*)h;
    int c4 = ch*2;
    float4 s0 = h4[(size_t)i*64 + c4], s1 = h4[(size_t)i*64 + c4 + 1];
    float a0=0,a1=0,a2=0,a3=0,b0=0,b1=0,b2=0,b3=0;
    #pragma unroll
    for (int q = 0; q < KNN; ++q) {
        float4 t0 = h4[(size_t)jn[q]*64 + c4];
        float4 t1 = h4[(size_t)jn[q]*64 + c4 + 1];
        a0+=t0.x; a1+=t0.y; a2+=t0.z; a3+=t0.w;
        b0+=t1.x; b1+=t1.y; b2+=t1.z; b3+=t1.w;
    }
    float v[8];
    v[0]=a0*c1+s0.x*c2; v[1]=a1*c1+s0.y*c2; v[2]=a2*c1+s0.z*c2; v[3]=a3*c1+s0.w*c2;
    v[4]=b0*c1+s1.x*c2; v[5]=b1*c1+s1.y*c2; v[6]=b2*c1+s1.z*c2; v[7]=b3*c1+s1.w*c2;
    int mb = i >> 7, row = i & 127, step = ch >> 2, kbyte = (ch & 3)*16;
    char* base = Aimg + (size_t)mb*(8*16384) + (size_t)step*16384;
    int off = swzoff(row, kbyte);
    split_store(v, base + off, base + 8192 + off);
}

// ---------------------------------------------------------------------------
// MFMA GEMM: C[128x128 tile] = bn_relu(A @ W). bf16 2-split, 3 passes.
// ---------------------------------------------------------------------------
__global__ __launch_bounds__(256,4) void gemm_mfma(
    const char* __restrict__ Aimg, const char* __restrict__ Wimg, int nstep,
    const float* __restrict__ bias,
    const float* __restrict__ gam, const float* __restrict__ bet,
    const float* __restrict__ mu,  const float* __restrict__ var,
    float* __restrict__ out)
{
    __shared__ uint4 lds4[34816/16];
    char* lds  = (char*)lds4;
    char* Alds = lds;
    char* Wlds = lds + 16384;
    float* scs = (float*)(lds + 32768);
    float* shs = scs + 256;
    const int tid = threadIdx.x;
    const int lane = tid & 63, wave = tid >> 6;
    const int wm = wave >> 1, wn = wave & 1;
    const int mblk = blockIdx.x, nblk = blockIdx.y;

    if (tid < 256) {
        float s = gam[tid] / sqrtf(var[tid] + 1e-5f);
        scs[tid] = s;
        shs[tid] = bet[tid] + (bias[tid] - mu[tid]) * s;
    }

    const char* Ab = Aimg + (size_t)mblk * nstep * 16384;
    const char* Wb = Wimg + (size_t)nblk * nstep * 16384;

    const char* gbase; char* lbase;
    int soff;
    if (wave < 2) { gbase = Ab;  lbase = Alds; soff = wave*8192; }
    else          { gbase = Wb;  lbase = Wlds; soff = (wave-2)*8192; }

    f32x4 acc[4][4];
    #pragma unroll
    for (int m = 0; m < 4; ++m)
        #pragma unroll
        for (int n = 0; n < 4; ++n) acc[m][n] = (f32x4){0.f,0.f,0.f,0.f};

    for (int s = 0; s < nstep; ++s) {
        #pragma unroll
        for (int i = 0; i < 8; ++i) {
            int off = soff + i*1024;
            __builtin_amdgcn_global_load_lds(
                (const __attribute__((address_space(1))) void*)(gbase + (size_t)s*16384 + off + lane*16),
                (__attribute__((address_space(3))) void*)(lbase + off), 16, 0, 0);
        }
        __syncthreads();
        const int kb = (lane >> 4) * 16;
        bf16x8 ah[4], al[4];
        #pragma unroll
        for (int m = 0; m < 4; ++m) {
            int row = wm*64 + m*16 + (lane & 15);
            int off = swzoff(row, kb);
            ah[m] = *(const bf16x8*)(Alds + off);
            al[m] = *(const bf16x8*)(Alds + 8192 + off);
        }
        #pragma unroll
        for (int n = 0; n < 4; ++n) {
            int col = wn*64 + n*16 + (lane & 15);
            int off = swzoff(col, kb);
            bf16x8 bh = *(const bf16x8*)(Wlds + off);
            bf16x8 bl = *(const bf16x8*)(Wlds + 8192 + off);
            #pragma unroll
            for (int m = 0; m < 4; ++m) {
                acc[m][n] = __builtin_amdgcn_mfma_f32_16x16x32_bf16(ah[m], bh, acc[m][n], 0, 0, 0);
                acc[m][n] = __builtin_amdgcn_mfma_f32_16x16x32_bf16(al[m], bh, acc[m][n], 0, 0, 0);
                acc[m][n] = __builtin_amdgcn_mfma_f32_16x16x32_bf16(ah[m], bl, acc[m][n], 0, 0, 0);
            }
        }
        __syncthreads();
    }

    #pragma unroll
    for (int n = 0; n < 4; ++n) {
        int c = nblk*128 + wn*64 + n*16 + (lane & 15);
        float sc = scs[c], sh = shs[c];
        #pragma unroll
        for (int m = 0; m < 4; ++m) {
            int r0 = mblk*128 + wm*64 + m*16 + (lane >> 4)*4;
            #pragma unroll
            for (int q = 0; q < 4; ++q) {
                float v = acc[m][n][q]*sc + sh;
                out[(size_t)(r0+q)*256 + c] = fmaxf(v, 0.f);
            }
        }
    }
}

// ---------------------------------------------------------------------------
// Readout stage 1: gate[r] = relu(h3[r]·gate_w + gate_b). One wave per row,
// float4 coalesced, 6-level shuffle reduce. 2048 blocks (grid-stride 4 rows).
// ---------------------------------------------------------------------------
__global__ __launch_bounds__(256) void gate_kernel(const float* __restrict__ h3,
                                                   const float* __restrict__ gate_w,
                                                   const float* __restrict__ gate_b,
                                                   float* __restrict__ gate)
{
    const int lane = threadIdx.x & 63;
    const int gw = (blockIdx.x*256 + threadIdx.x) >> 6;   // global wave id, 8192 waves
    float4 w4 = ((const float4*)gate_w)[lane];
    float gb = gate_b[0];
    #pragma unroll
    for (int it = 0; it < 4; ++it) {
        int r = gw + it*8192;
        float4 v = ((const float4*)(h3 + (size_t)r*HF))[lane];
        float s = v.x*w4.x + v.y*w4.y + v.z*w4.z + v.w*w4.w;
        #pragma unroll
        for (int o = 32; o > 0; o >>= 1) s += __shfl_xor(s, o, 64);
        if (lane == 0) gate[r] = fmaxf(s + gb, 0.f);
    }
}

// ---------------------------------------------------------------------------
// Readout stage 2: per-graph softmax over 512 gates -> attn.
// ---------------------------------------------------------------------------
__device__ __forceinline__ float blk_sum256(float v, volatile float* red)
{
    #pragma unroll
    for (int o = 32; o > 0; o >>= 1) v += __shfl_xor(v, o, 64);
    __syncthreads();
    if ((threadIdx.x & 63) == 0) red[threadIdx.x >> 6] = v;
    __syncthreads();
    return (red[0] + red[1]) + (red[2] + red[3]);
}

__global__ __launch_bounds__(256) void attn_kernel(const float* __restrict__ gate,
                                                   float* __restrict__ attn)
{
    int g = blockIdx.x, tid = threadIdx.x;
    __shared__ float red[4];
    float g0 = gate[g*NND + tid];
    float g1 = gate[g*NND + 256 + tid];
    float m = fmaxf(g0, g1);
    #pragma unroll
    for (int o = 32; o > 0; o >>= 1) m = fmaxf(m, __shfl_xor(m, o, 64));
    if ((tid & 63) == 0) red[tid >> 6] = m;
    __syncthreads();
    m = fmaxf(fmaxf(red[0], red[1]), fmaxf(red[2], red[3]));
    float e0 = expf(g0 - m), e1 = expf(g1 - m);
    float S = blk_sum256(e0 + e1, red);
    attn[g*NND + tid]       = e0 / S;
    attn[g*NND + 256 + tid] = e1 / S;
}

// ---------------------------------------------------------------------------
// Readout stage 3: gembp[s][g][f] = sum_{n in subset s} attn[n]*h3[n][f].
// Grid (NBG, 4); block 256 = 4 waves x 32 nodes; float4 per lane (full row).
// ---------------------------------------------------------------------------
__global__ __launch_bounds__(256) void gemb_kernel(const float* __restrict__ h3,
                                                   const float* __restrict__ attn,
                                                   float* __restrict__ gembp)
{
    const int g = blockIdx.x, s = blockIdx.y;
    const int tid = threadIdx.x, lane = tid & 63, w = tid >> 6;
    __shared__ float at[128];
    __shared__ float red4[4][HF];
    if (tid < 128) at[tid] = attn[g*NND + s*128 + tid];
    __syncthreads();
    const float* hb = h3 + (size_t)(g*NND + s*128 + w*32) * HF;
    float4 acc = make_float4(0.f, 0.f, 0.f, 0.f);
    #pragma unroll 4
    for (int n = 0; n < 32; ++n) {
        float a = at[w*32 + n];
        float4 v = ((const float4*)(hb + (size_t)n*HF))[lane];
        acc.x = fmaf(a, v.x, acc.x); acc.y = fmaf(a, v.y, acc.y);
        acc.z = fmaf(a, v.z, acc.z); acc.w = fmaf(a, v.w, acc.w);
    }
    *(float4*)&red4[w][lane*4] = acc;
    __syncthreads();
    if (tid < HF) {
        float sum = (red4[0][tid] + red4[1][tid]) + (red4[2][tid] + red4[3][tid]);
        gembp[((size_t)s*NBG + g)*HF + tid] = sum;
    }
}

// ---------------------------------------------------------------------------
// Readout stage 4: heads. gemb = sum of 4 partials; affinity + pose.
// ---------------------------------------------------------------------------
__global__ __launch_bounds__(256) void heads_kernel(
    const float* __restrict__ gembp,
    const float* __restrict__ aff_w,  const float* __restrict__ aff_b,
    const float* __restrict__ rl_w1,  const float* __restrict__ rl_b1,
    const float* __restrict__ rl_w2,  const float* __restrict__ rl_b2,
    float* __restrict__ out)
{
    int g = blockIdx.x, tid = threadIdx.x;
    __shared__ float gemb[HF];
    __shared__ float red[4];
    float acc = (gembp[((size_t)0*NBG + g)*HF + tid] + gembp[((size_t)1*NBG + g)*HF + tid])
              + (gembp[((size_t)2*NBG + g)*HF + tid] + gembp[((size_t)3*NBG + g)*HF + tid]);
    gemb[tid] = acc;
    __syncthreads();

    float sa = blk_sum256(acc * aff_w[tid], red);
    if (tid == 0) out[g] = sa + aff_b[0];

    float t = rl_b1[tid];
    #pragma unroll 4
    for (int k2 = 0; k2 < HF; ++k2)
        t = fmaf(gemb[k2], rl_w1[(size_t)k2*HF + tid], t);
    t = fmaxf(t, 0.f);
    float s0 = blk_sum256(t * rl_w2[(size_t)tid*3 + 0], red);
    if (tid == 0) out[128 + g*3 + 0] = s0 + rl_b2[0];
    float s1 = blk_sum256(t * rl_w2[(size_t)tid*3 + 1], red);
    if (tid == 0) out[128 + g*3 + 1] = s1 + rl_b2[1];
    float s2 = blk_sum256(t * rl_w2[(size_t)tid*3 + 2], red);
    if (tid == 0) out[128 + g*3 + 2] = s2 + rl_b2[2];
}

// ---------------------------------------------------------------------------
extern "C" void kernel_launch(void* const* d_in, const int* in_sizes, int n_in,
                              void* d_out, int out_size, void* d_ws, size_t ws_size,
                              hipStream_t stream)
{
    const float* x      = (const float*)d_in[0];
    const float* pos    = (const float*)d_in[1];
    const float* W1     = (const float*)d_in[2];
    const float* b1     = (const float*)d_in[3];
    const float* W2     = (const float*)d_in[4];
    const float* b2     = (const float*)d_in[5];
    const float* W3     = (const float*)d_in[6];
    const float* b3     = (const float*)d_in[7];
    const float* g1     = (const float*)d_in[8];
    const float* be1    = (const float*)d_in[9];
    const float* m1     = (const float*)d_in[10];
    const float* v1     = (const float*)d_in[11];
    const float* g2     = (const float*)d_in[12];
    const float* be2    = (const float*)d_in[13];
    const float* m2     = (const float*)d_in[14];
    const float* v2     = (const float*)d_in[15];
    const float* g3     = (const float*)d_in[16];
    const float* be3    = (const float*)d_in[17];
    const float* m3     = (const float*)d_in[18];
    const float* v3     = (const float*)d_in[19];
    const float* gate_w = (const float*)d_in[20];
    const float* gate_b = (const float*)d_in[21];
    const float* aff_w  = (const float*)d_in[22];
    const float* aff_b  = (const float*)d_in[23];
    const float* rl_w1  = (const float*)d_in[24];
    const float* rl_b1  = (const float*)d_in[25];
    const float* rl_w2  = (const float*)d_in[26];
    const float* rl_b2  = (const float*)d_in[27];
    float* out = (float*)d_out;

    // workspace layout (~68.6 MB extent, same as previous rounds)
    char* wsb = (char*)d_ws;
    unsigned short* nbr = (unsigned short*)wsb;               // 786,432 B
    char* Wimg1 = wsb + 786432;                               // 163,840 B
    char* Wimg2 = Wimg1 + (size_t)2*NSTEP1*16384;             // 262,144 B
    char* Wimg3 = Wimg2 + (size_t)2*8*16384;                  // 262,144 B
    float* h    = (float*)(Wimg3 + (size_t)2*8*16384);        // 33.5 MB
    char* Aimg  = (char*)(h + (size_t)NB_TOT*HF);             // 33.5 MB
    // readout scratch aliases Aimg (dead after gemm3 reads it)
    float* gate  = (float*)Aimg;                              // 128 KB
    float* attn  = gate + NB_TOT;                             // 128 KB
    float* gembp = attn + NB_TOT;                             // 512 KB

    knn_kernel<<<NBG*8, 256, 0, stream>>>(pos, nbr);
    prew_kernel<<<(2*NSTEP1*512)/256, 256, 0, stream>>>(W1, 131, NSTEP1, Wimg1);
    prew_kernel<<<(2*8*512)/256, 256, 0, stream>>>(W2, 256, 8, Wimg2);
    prew_kernel<<<(2*8*512)/256, 256, 0, stream>>>(W3, 256, 8, Wimg3);

    agg_first<<<(NB_TOT*20)/256, 256, 0, stream>>>(x, pos, nbr, Aimg);
    gemm_mfma<<<dim3(NB_TOT/128, 2), 256, 0, stream>>>(Aimg, Wimg1, NSTEP1,
        b1, g1, be1, m1, v1, h);
    agg_h<<<(NB_TOT*32)/256, 256, 0, stream>>>(h, nbr, Aimg);
    gemm_mfma<<<dim3(NB_TOT/128, 2), 256, 0, stream>>>(Aimg, Wimg2, 8,
        b2, g2, be2, m2, v2, h);
    agg_h<<<(NB_TOT*32)/256, 256, 0, stream>>>(h, nbr, Aimg);
    gemm_mfma<<<dim3(NB_TOT/128, 2), 256, 0, stream>>>(Aimg, Wimg3, 8,
        b3, g3, be3, m3, v3, h);

    gate_kernel<<<2048, 256, 0, stream>>>(h, gate_w, gate_b, gate);
    attn_kernel<<<NBG, 256, 0, stream>>>(gate, attn);
    gemb_kernel<<<dim3(NBG, 4), 256, 0, stream>>>(h, attn, gembp);
    heads_kernel<<<NBG, 256, 0, stream>>>(gembp, aff_w, aff_b,
                                          rl_w1, rl_b1, rl_w2, rl_b2, out);
}

// Round 8
// 248.020 us; speedup vs baseline: 3.1807x; 1.2582x over previous
//
#include <hip/hip_runtime.h>
#include <hip/hip_bf16.h>
#include <math.h>
#include <float.h>

#define NBG 128      // graphs
#define NND 512      // nodes per graph
#define KNN 6
#define NB_TOT (NBG*NND)
#define HF 256
#define NSTEP1 5     // layer-1 K padded to 160 (131 real)

typedef short bf16x8 __attribute__((ext_vector_type(8)));
typedef float f32x4 __attribute__((ext_vector_type(4)));

// byte offset of element (row, kbyte) in an 8-KB [128 rows][32 k] bf16 plane,
// XOR-swizzled so 16-lane frag reads cover all eight 16-B slots (2-way free).
__device__ __forceinline__ int swzoff(int row, int kbyte) {
    return (row*64 + kbyte) ^ (((row>>1)&3)<<4);
}

__device__ __forceinline__ void split_store(const float* v, char* hi_p, char* lo_p) {
    bf16x8 hi, lo;
    #pragma unroll
    for (int j = 0; j < 8; ++j) {
        __hip_bfloat16 h = __float2bfloat16(v[j]);
        float hf = __bfloat162float(h);
        __hip_bfloat16 l = __float2bfloat16(v[j] - hf);
        hi[j] = *(short*)&h;
        lo[j] = *(short*)&l;
    }
    *(bf16x8*)hi_p = hi;
    *(bf16x8*)lo_p = lo;
}

// XCD-aware bijective block swizzle (grid must be a multiple of 8):
// XCD k (dispatch round-robin bid%8) gets the contiguous work range
// [k*grid/8, (k+1)*grid/8) -> graph-local gathers stay in one L2.
__device__ __forceinline__ int xcd_swz(int bid, int grid) {
    return (bid & 7) * (grid >> 3) + (bid >> 3);
}

// ---------------------------------------------------------------------------
// kNN v4b: 8 blocks/graph, 4 lanes/node (128 candidates each), branchless
// (d2,idx) carry-chain insertion, two independent chains per lane (ILP).
// ---------------------------------------------------------------------------
__global__ __launch_bounds__(256) void knn_kernel(const float* __restrict__ pos,
                                                  unsigned short* __restrict__ nbr)
{
    const int blk = blockIdx.x;           // 1024 blocks
    const int g = blk >> 3;
    const int chunk = (blk & 7) * 64;
    const int tid = threadIdx.x;
    const int node = chunk + (tid >> 2);  // local node id
    const int sub = tid & 3;

    __shared__ float4 p4[NND + (NND>>6)]; // padded: idx j -> j + (j>>6)
    const float* pg = pos + (size_t)g * NND * 3;
    for (int n = tid; n < NND; n += 256) {
        float x = pg[n*3+0], y = pg[n*3+1], z = pg[n*3+2];
        p4[n + (n>>6)] = make_float4(x, y, z, x*x + y*y + z*z);
    }
    __syncthreads();

    const float4 pi = p4[node + (node>>6)];
    const float m2x = -2.0f*pi.x, m2y = -2.0f*pi.y, m2z = -2.0f*pi.z;

    float bdA[KNN], bdB[KNN]; int biA[KNN], biB[KNN];
    #pragma unroll
    for (int q = 0; q < KNN; ++q) {
        bdA[q] = FLT_MAX; biA[q] = 0x7fffffff;
        bdB[q] = FLT_MAX; biB[q] = 0x7fffffff;
    }

    const int j0 = sub * 128;
    const float4* baseA = &p4[sub*130];
    const float4* baseB = &p4[sub*130 + 65];

    #pragma unroll 2
    for (int t = 0; t < 64; ++t) {
        int ja = j0 + t, jb = j0 + 64 + t;
        float4 pa = baseA[t];
        float4 pb = baseB[t];
        float da = fmaf(m2z, pa.z, fmaf(m2y, pa.y, fmaf(m2x, pa.x, pa.w)));
        float db = fmaf(m2z, pb.z, fmaf(m2y, pb.y, fmaf(m2x, pb.x, pb.w)));
        da = (ja == node) ? FLT_MAX : da;
        db = (jb == node) ? FLT_MAX : db;
        float ca = da; int ia = ja;
        float cb = db; int ib = jb;
        #pragma unroll
        for (int q = 0; q < KNN; ++q) {
            bool sa = ca < bdA[q];
            float t1 = sa ? ca : bdA[q]; float t2 = sa ? bdA[q] : ca;
            int   t3 = sa ? ia : biA[q]; int   t4 = sa ? biA[q] : ia;
            bdA[q] = t1; ca = t2; biA[q] = t3; ia = t4;
            bool sb = cb < bdB[q];
            float u1 = sb ? cb : bdB[q]; float u2 = sb ? bdB[q] : cb;
            int   u3 = sb ? ib : biB[q]; int   u4 = sb ? biB[q] : ib;
            bdB[q] = u1; cb = u2; biB[q] = u3; ib = u4;
        }
    }

    float ld[KNN]; int li[KNN];
    #pragma unroll
    for (int q = 0; q < KNN; ++q) {
        float ad = bdA[q], xd = bdB[KNN-1-q];
        int   ai = biA[q], xi = biB[KNN-1-q];
        bool t = (ad < xd) || (ad == xd && ai < xi);
        ld[q] = t ? ad : xd;
        li[q] = t ? ai : xi;
    }
    #pragma unroll
    for (int pass = 0; pass < KNN-1; ++pass)
        #pragma unroll
        for (int a = 0; a < KNN-1-pass; ++a) {
            int b = a+1;
            bool sw = (ld[b] < ld[a]) || (ld[b] == ld[a] && li[b] < li[a]);
            float td = sw ? ld[b] : ld[a]; float ud = sw ? ld[a] : ld[b];
            int   ti = sw ? li[b] : li[a]; int   ui = sw ? li[a] : li[b];
            ld[a] = td; li[a] = ti; ld[b] = ud; li[b] = ui;
        }

    #pragma unroll
    for (int mi = 0; mi < 2; ++mi) {
        const int mask = 1 << mi;
        float od[KNN]; int oi[KNN];
        #pragma unroll
        for (int q = 0; q < KNN; ++q) {
            od[q] = __shfl_xor(ld[q], mask);
            oi[q] = __shfl_xor(li[q], mask);
        }
        #pragma unroll
        for (int q = 0; q < KNN; ++q) {
            float ad = ld[q], xd = od[KNN-1-q];
            int   ai = li[q], xi = oi[KNN-1-q];
            bool t = (ad < xd) || (ad == xd && ai < xi);
            ld[q] = t ? ad : xd;
            li[q] = t ? ai : xi;
        }
        #pragma unroll
        for (int pass = 0; pass < KNN-1; ++pass)
            #pragma unroll
            for (int a = 0; a < KNN-1-pass; ++a) {
                int b = a+1;
                bool sw = (ld[b] < ld[a]) || (ld[b] == ld[a] && li[b] < li[a]);
                float td = sw ? ld[b] : ld[a]; float ud = sw ? ld[a] : ld[b];
                int   ti = sw ? li[b] : li[a]; int   ui = sw ? li[a] : li[b];
                ld[a] = td; li[a] = ti; ld[b] = ud; li[b] = ui;
            }
    }

    if (sub == 0) {
        int base = (g*NND + node)*KNN;
        #pragma unroll
        for (int q = 0; q < KNN; ++q) nbr[base+q] = (unsigned short)li[q];
    }
}

// ---------------------------------------------------------------------------
// W pre-pass: build swizzled hi/lo bf16 LDS images of W.
// ---------------------------------------------------------------------------
__global__ __launch_bounds__(256) void prew_kernel(const float* __restrict__ W,
                                                   int K, int nstep,
                                                   char* __restrict__ Wimg)
{
    int gid = blockIdx.x*256 + threadIdx.x;       // 2*nstep*512 threads
    int per_nb = nstep*512;
    int nb = gid / per_nb;
    int r  = gid - nb*per_nb;
    int step = r >> 9;
    int r2 = r & 511;
    int cl = r2 >> 2;
    int kc = (r2 & 3) * 8;
    float v[8];
    #pragma unroll
    for (int j = 0; j < 8; ++j) {
        int gk = step*32 + kc + j;
        v[j] = (gk < K) ? W[(size_t)gk*256 + nb*128 + cl] : 0.f;
    }
    char* base = Wimg + (size_t)nb*nstep*16384 + (size_t)step*16384;
    int off = swzoff(cl, kc*2);
    split_store(v, base + off, base + 8192 + off);
}

// ---------------------------------------------------------------------------
// agg_first: A1 image from concat(x,pos). XCD-swizzled blocks.
// ---------------------------------------------------------------------------
__global__ __launch_bounds__(256) void agg_first(const float* __restrict__ x,
                                                 const float* __restrict__ pos,
                                                 const unsigned short* __restrict__ nbr,
                                                 char* __restrict__ Aimg)
{
    int gid = xcd_swz(blockIdx.x, gridDim.x)*256 + threadIdx.x;   // NB_TOT*20
    int i = gid / 20, ch = gid - i*20;
    const float rs = 1.0f/sqrtf(7.0f);
    const float c1 = rs*rs, c2 = 1.0f/7.0f;
    const int gbase = i & ~(NND-1);
    float v[8];
    if (ch < 16) {
        int jn[KNN];
        #pragma unroll
        for (int q = 0; q < KNN; ++q) jn[q] = gbase + nbr[i*KNN+q];
        const float4* x4 = (const float4*)x;
        int c4 = ch*2;
        float4 s0 = x4[(size_t)i*32 + c4], s1 = x4[(size_t)i*32 + c4 + 1];
        float a0=0,a1=0,a2=0,a3=0,b0=0,b1=0,b2=0,b3=0;
        #pragma unroll
        for (int q = 0; q < KNN; ++q) {
            float4 t0 = x4[(size_t)jn[q]*32 + c4];
            float4 t1 = x4[(size_t)jn[q]*32 + c4 + 1];
            a0+=t0.x; a1+=t0.y; a2+=t0.z; a3+=t0.w;
            b0+=t1.x; b1+=t1.y; b2+=t1.z; b3+=t1.w;
        }
        v[0]=a0*c1+s0.x*c2; v[1]=a1*c1+s0.y*c2; v[2]=a2*c1+s0.z*c2; v[3]=a3*c1+s0.w*c2;
        v[4]=b0*c1+s1.x*c2; v[5]=b1*c1+s1.y*c2; v[6]=b2*c1+s1.z*c2; v[7]=b3*c1+s1.w*c2;
    } else if (ch == 16) {
        int jn[KNN];
        #pragma unroll
        for (int q = 0; q < KNN; ++q) jn[q] = gbase + nbr[i*KNN+q];
        float ax=0, ay=0, az=0;
        #pragma unroll
        for (int q = 0; q < KNN; ++q) {
            ax += pos[(size_t)jn[q]*3+0];
            ay += pos[(size_t)jn[q]*3+1];
            az += pos[(size_t)jn[q]*3+2];
        }
        v[0] = ax*c1 + pos[(size_t)i*3+0]*c2;
        v[1] = ay*c1 + pos[(size_t)i*3+1]*c2;
        v[2] = az*c1 + pos[(size_t)i*3+2]*c2;
        v[3]=v[4]=v[5]=v[6]=v[7]=0.f;
    } else {
        #pragma unroll
        for (int j = 0; j < 8; ++j) v[j] = 0.f;
    }
    int mb = i >> 7, row = i & 127, step = ch >> 2, kbyte = (ch & 3)*16;
    char* base = Aimg + (size_t)mb*(NSTEP1*16384) + (size_t)step*16384;
    int off = swzoff(row, kbyte);
    split_store(v, base + off, base + 8192 + off);
}

// ---------------------------------------------------------------------------
// agg_h: A image from 256-dim h. XCD-swizzled blocks (graph-local gather
// stays in one XCD's L2: 64 blocks/graph, 1024 blocks/XCD = 16 graphs).
// ---------------------------------------------------------------------------
__global__ __launch_bounds__(256) void agg_h(const float* __restrict__ h,
                                             const unsigned short* __restrict__ nbr,
                                             char* __restrict__ Aimg)
{
    int gid = xcd_swz(blockIdx.x, gridDim.x)*256 + threadIdx.x;   // NB_TOT*32
    int i = gid >> 5, ch = gid & 31;
    const float rs = 1.0f/sqrtf(7.0f);
    const float c1 = rs*rs, c2 = 1.0f/7.0f;
    const int gbase = i & ~(NND-1);
    int jn[KNN];
    #pragma unroll
    for (int q = 0; q < KNN; ++q) jn[q] = gbase + nbr[i*KNN+q];
    const float4* h4 = (const float4*)h;
    int c4 = ch*2;
    float4 s0 = h4[(size_t)i*64 + c4], s1 = h4[(size_t)i*64 + c4 + 1];
    float a0=0,a1=0,a2=0,a3=0,b0=0,b1=0,b2=0,b3=0;
    #pragma unroll
    for (int q = 0; q < KNN; ++q) {
        float4 t0 = h4[(size_t)jn[q]*64 + c4];
        float4 t1 = h4[(size_t)jn[q]*64 + c4 + 1];
        a0+=t0.x; a1+=t0.y; a2+=t0.z; a3+=t0.w;
        b0+=t1.x; b1+=t1.y; b2+=t1.z; b3+=t1.w;
    }
    float v[8];
    v[0]=a0*c1+s0.x*c2; v[1]=a1*c1+s0.y*c2; v[2]=a2*c1+s0.z*c2; v[3]=a3*c1+s0.w*c2;
    v[4]=b0*c1+s1.x*c2; v[5]=b1*c1+s1.y*c2; v[6]=b2*c1+s1.z*c2; v[7]=b3*c1+s1.w*c2;
    int mb = i >> 7, row = i & 127, step = ch >> 2, kbyte = (ch & 3)*16;
    char* base = Aimg + (size_t)mb*(8*16384) + (size_t)step*16384;
    int off = swzoff(row, kbyte);
    split_store(v, base + off, base + 8192 + off);
}

// ---------------------------------------------------------------------------
// MFMA GEMM: C[128x128 tile] = bn_relu(A @ W). bf16 2-split, 3 passes.
// ---------------------------------------------------------------------------
__global__ __launch_bounds__(256,4) void gemm_mfma(
    const char* __restrict__ Aimg, const char* __restrict__ Wimg, int nstep,
    const float* __restrict__ bias,
    const float* __restrict__ gam, const float* __restrict__ bet,
    const float* __restrict__ mu,  const float* __restrict__ var,
    float* __restrict__ out)
{
    __shared__ uint4 lds4[34816/16];
    char* lds  = (char*)lds4;
    char* Alds = lds;
    char* Wlds = lds + 16384;
    float* scs = (float*)(lds + 32768);
    float* shs = scs + 256;
    const int tid = threadIdx.x;
    const int lane = tid & 63, wave = tid >> 6;
    const int wm = wave >> 1, wn = wave & 1;
    const int mblk = blockIdx.x, nblk = blockIdx.y;

    if (tid < 256) {
        float s = gam[tid] / sqrtf(var[tid] + 1e-5f);
        scs[tid] = s;
        shs[tid] = bet[tid] + (bias[tid] - mu[tid]) * s;
    }

    const char* Ab = Aimg + (size_t)mblk * nstep * 16384;
    const char* Wb = Wimg + (size_t)nblk * nstep * 16384;

    const char* gbase; char* lbase;
    int soff;
    if (wave < 2) { gbase = Ab;  lbase = Alds; soff = wave*8192; }
    else          { gbase = Wb;  lbase = Wlds; soff = (wave-2)*8192; }

    f32x4 acc[4][4];
    #pragma unroll
    for (int m = 0; m < 4; ++m)
        #pragma unroll
        for (int n = 0; n < 4; ++n) acc[m][n] = (f32x4){0.f,0.f,0.f,0.f};

    for (int s = 0; s < nstep; ++s) {
        #pragma unroll
        for (int i = 0; i < 8; ++i) {
            int off = soff + i*1024;
            __builtin_amdgcn_global_load_lds(
                (const __attribute__((address_space(1))) void*)(gbase + (size_t)s*16384 + off + lane*16),
                (__attribute__((address_space(3))) void*)(lbase + off), 16, 0, 0);
        }
        __syncthreads();
        const int kb = (lane >> 4) * 16;
        bf16x8 ah[4], al[4];
        #pragma unroll
        for (int m = 0; m < 4; ++m) {
            int row = wm*64 + m*16 + (lane & 15);
            int off = swzoff(row, kb);
            ah[m] = *(const bf16x8*)(Alds + off);
            al[m] = *(const bf16x8*)(Alds + 8192 + off);
        }
        #pragma unroll
        for (int n = 0; n < 4; ++n) {
            int col = wn*64 + n*16 + (lane & 15);
            int off = swzoff(col, kb);
            bf16x8 bh = *(const bf16x8*)(Wlds + off);
            bf16x8 bl = *(const bf16x8*)(Wlds + 8192 + off);
            #pragma unroll
            for (int m = 0; m < 4; ++m) {
                acc[m][n] = __builtin_amdgcn_mfma_f32_16x16x32_bf16(ah[m], bh, acc[m][n], 0, 0, 0);
                acc[m][n] = __builtin_amdgcn_mfma_f32_16x16x32_bf16(al[m], bh, acc[m][n], 0, 0, 0);
                acc[m][n] = __builtin_amdgcn_mfma_f32_16x16x32_bf16(ah[m], bl, acc[m][n], 0, 0, 0);
            }
        }
        __syncthreads();
    }

    #pragma unroll
    for (int n = 0; n < 4; ++n) {
        int c = nblk*128 + wn*64 + n*16 + (lane & 15);
        float sc = scs[c], sh = shs[c];
        #pragma unroll
        for (int m = 0; m < 4; ++m) {
            int r0 = mblk*128 + wm*64 + m*16 + (lane >> 4)*4;
            #pragma unroll
            for (int q = 0; q < 4; ++q) {
                float v = acc[m][n][q]*sc + sh;
                out[(size_t)(r0+q)*256 + c] = fmaxf(v, 0.f);
            }
        }
    }
}

// ---------------------------------------------------------------------------
// Readout stage 1: gate[r] = relu(h3[r]·gate_w + gate_b).
// ---------------------------------------------------------------------------
__global__ __launch_bounds__(256) void gate_kernel(const float* __restrict__ h3,
                                                   const float* __restrict__ gate_w,
                                                   const float* __restrict__ gate_b,
                                                   float* __restrict__ gate)
{
    const int lane = threadIdx.x & 63;
    const int gw = (blockIdx.x*256 + threadIdx.x) >> 6;   // global wave id, 8192 waves
    float4 w4 = ((const float4*)gate_w)[lane];
    float gb = gate_b[0];
    #pragma unroll
    for (int it = 0; it < 4; ++it) {
        int r = gw + it*8192;
        float4 v = ((const float4*)(h3 + (size_t)r*HF))[lane];
        float s = v.x*w4.x + v.y*w4.y + v.z*w4.z + v.w*w4.w;
        #pragma unroll
        for (int o = 32; o > 0; o >>= 1) s += __shfl_xor(s, o, 64);
        if (lane == 0) gate[r] = fmaxf(s + gb, 0.f);
    }
}

// ---------------------------------------------------------------------------
// Readout stage 2: per-graph softmax over 512 gates -> attn.
// ---------------------------------------------------------------------------
__device__ __forceinline__ float blk_sum256(float v, volatile float* red)
{
    #pragma unroll
    for (int o = 32; o > 0; o >>= 1) v += __shfl_xor(v, o, 64);
    __syncthreads();
    if ((threadIdx.x & 63) == 0) red[threadIdx.x >> 6] = v;
    __syncthreads();
    return (red[0] + red[1]) + (red[2] + red[3]);
}

__global__ __launch_bounds__(256) void attn_kernel(const float* __restrict__ gate,
                                                   float* __restrict__ attn)
{
    int g = blockIdx.x, tid = threadIdx.x;
    __shared__ float red[4];
    float g0 = gate[g*NND + tid];
    float g1 = gate[g*NND + 256 + tid];
    float m = fmaxf(g0, g1);
    #pragma unroll
    for (int o = 32; o > 0; o >>= 1) m = fmaxf(m, __shfl_xor(m, o, 64));
    if ((tid & 63) == 0) red[tid >> 6] = m;
    __syncthreads();
    m = fmaxf(fmaxf(red[0], red[1]), fmaxf(red[2], red[3]));
    float e0 = expf(g0 - m), e1 = expf(g1 - m);
    float S = blk_sum256(e0 + e1, red);
    attn[g*NND + tid]       = e0 / S;
    attn[g*NND + 256 + tid] = e1 / S;
}

// ---------------------------------------------------------------------------
// Readout stage 3: gembp[s][g][f] = sum_{n in subset s} attn[n]*h3[n][f].
// ---------------------------------------------------------------------------
__global__ __launch_bounds__(256) void gemb_kernel(const float* __restrict__ h3,
                                                   const float* __restrict__ attn,
                                                   float* __restrict__ gembp)
{
    const int g = blockIdx.x, s = blockIdx.y;
    const int tid = threadIdx.x, lane = tid & 63, w = tid >> 6;
    __shared__ float at[128];
    __shared__ float red4[4][HF];
    if (tid < 128) at[tid] = attn[g*NND + s*128 + tid];
    __syncthreads();
    const float* hb = h3 + (size_t)(g*NND + s*128 + w*32) * HF;
    float4 acc = make_float4(0.f, 0.f, 0.f, 0.f);
    #pragma unroll 4
    for (int n = 0; n < 32; ++n) {
        float a = at[w*32 + n];
        float4 v = ((const float4*)(hb + (size_t)n*HF))[lane];
        acc.x = fmaf(a, v.x, acc.x); acc.y = fmaf(a, v.y, acc.y);
        acc.z = fmaf(a, v.z, acc.z); acc.w = fmaf(a, v.w, acc.w);
    }
    *(float4*)&red4[w][lane*4] = acc;
    __syncthreads();
    if (tid < HF) {
        float sum = (red4[0][tid] + red4[1][tid]) + (red4[2][tid] + red4[3][tid]);
        gembp[((size_t)s*NBG + g)*HF + tid] = sum;
    }
}

// ---------------------------------------------------------------------------
// Readout stage 4: heads. gemb = sum of 4 partials; affinity + pose.
// ---------------------------------------------------------------------------
__global__ __launch_bounds__(256) void heads_kernel(
    const float* __restrict__ gembp,
    const float* __restrict__ aff_w,  const float* __restrict__ aff_b,
    const float* __restrict__ rl_w1,  const float* __restrict__ rl_b1,
    const float* __restrict__ rl_w2,  const float* __restrict__ rl_b2,
    float* __restrict__ out)
{
    int g = blockIdx.x, tid = threadIdx.x;
    __shared__ float gemb[HF];
    __shared__ float red[4];
    float acc = (gembp[((size_t)0*NBG + g)*HF + tid] + gembp[((size_t)1*NBG + g)*HF + tid])
              + (gembp[((size_t)2*NBG + g)*HF + tid] + gembp[((size_t)3*NBG + g)*HF + tid]);
    gemb[tid] = acc;
    __syncthreads();

    float sa = blk_sum256(acc * aff_w[tid], red);
    if (tid == 0) out[g] = sa + aff_b[0];

    float t = rl_b1[tid];
    #pragma unroll 4
    for (int k2 = 0; k2 < HF; ++k2)
        t = fmaf(gemb[k2], rl_w1[(size_t)k2*HF + tid], t);
    t = fmaxf(t, 0.f);
    float s0 = blk_sum256(t * rl_w2[(size_t)tid*3 + 0], red);
    if (tid == 0) out[128 + g*3 + 0] = s0 + rl_b2[0];
    float s1 = blk_sum256(t * rl_w2[(size_t)tid*3 + 1], red);
    if (tid == 0) out[128 + g*3 + 1] = s1 + rl_b2[1];
    float s2 = blk_sum256(t * rl_w2[(size_t)tid*3 + 2], red);
    if (tid == 0) out[128 + g*3 + 2] = s2 + rl_b2[2];
}

// ---------------------------------------------------------------------------
extern "C" void kernel_launch(void* const* d_in, const int* in_sizes, int n_in,
                              void* d_out, int out_size, void* d_ws, size_t ws_size,
                              hipStream_t stream)
{
    const float* x      = (const float*)d_in[0];
    const float* pos    = (const float*)d_in[1];
    const float* W1     = (const float*)d_in[2];
    const float* b1     = (const float*)d_in[3];
    const float* W2     = (const float*)d_in[4];
    const float* b2     = (const float*)d_in[5];
    const float* W3     = (const float*)d_in[6];
    const float* b3     = (const float*)d_in[7];
    const float* g1     = (const float*)d_in[8];
    const float* be1    = (const float*)d_in[9];
    const float* m1     = (const float*)d_in[10];
    const float* v1     = (const float*)d_in[11];
    const float* g2     = (const float*)d_in[12];
    const float* be2    = (const float*)d_in[13];
    const float* m2     = (const float*)d_in[14];
    const float* v2     = (const float*)d_in[15];
    const float* g3     = (const float*)d_in[16];
    const float* be3    = (const float*)d_in[17];
    const float* m3     = (const float*)d_in[18];
    const float* v3     = (const float*)d_in[19];
    const float* gate_w = (const float*)d_in[20];
    const float* gate_b = (const float*)d_in[21];
    const float* aff_w  = (const float*)d_in[22];
    const float* aff_b  = (const float*)d_in[23];
    const float* rl_w1  = (const float*)d_in[24];
    const float* rl_b1  = (const float*)d_in[25];
    const float* rl_w2  = (const float*)d_in[26];
    const float* rl_b2  = (const float*)d_in[27];
    float* out = (float*)d_out;

    // workspace layout (~68.6 MB extent)
    char* wsb = (char*)d_ws;
    unsigned short* nbr = (unsigned short*)wsb;               // 786,432 B
    char* Wimg1 = wsb + 786432;                               // 163,840 B
    char* Wimg2 = Wimg1 + (size_t)2*NSTEP1*16384;             // 262,144 B
    char* Wimg3 = Wimg2 + (size_t)2*8*16384;                  // 262,144 B
    float* h    = (float*)(Wimg3 + (size_t)2*8*16384);        // 33.5 MB
    char* Aimg  = (char*)(h + (size_t)NB_TOT*HF);             // 33.5 MB
    // readout scratch aliases Aimg (dead after gemm3 reads it)
    float* gate  = (float*)Aimg;                              // 128 KB
    float* attn  = gate + NB_TOT;                             // 128 KB
    float* gembp = attn + NB_TOT;                             // 512 KB

    knn_kernel<<<NBG*8, 256, 0, stream>>>(pos, nbr);
    prew_kernel<<<(2*NSTEP1*512)/256, 256, 0, stream>>>(W1, 131, NSTEP1, Wimg1);
    prew_kernel<<<(2*8*512)/256, 256, 0, stream>>>(W2, 256, 8, Wimg2);
    prew_kernel<<<(2*8*512)/256, 256, 0, stream>>>(W3, 256, 8, Wimg3);

    agg_first<<<(NB_TOT*20)/256, 256, 0, stream>>>(x, pos, nbr, Aimg);
    gemm_mfma<<<dim3(NB_TOT/128, 2), 256, 0, stream>>>(Aimg, Wimg1, NSTEP1,
        b1, g1, be1, m1, v1, h);
    agg_h<<<(NB_TOT*32)/256, 256, 0, stream>>>(h, nbr, Aimg);
    gemm_mfma<<<dim3(NB_TOT/128, 2), 256, 0, stream>>>(Aimg, Wimg2, 8,
        b2, g2, be2, m2, v2, h);
    agg_h<<<(NB_TOT*32)/256, 256, 0, stream>>>(h, nbr, Aimg);
    gemm_mfma<<<dim3(NB_TOT/128, 2), 256, 0, stream>>>(Aimg, Wimg3, 8,
        b3, g3, be3, m3, v3, h);

    gate_kernel<<<2048, 256, 0, stream>>>(h, gate_w, gate_b, gate);
    attn_kernel<<<NBG, 256, 0, stream>>>(gate, attn);
    gemb_kernel<<<dim3(NBG, 4), 256, 0, stream>>>(h, attn, gembp);
    heads_kernel<<<NBG, 256, 0, stream>>>(gembp, aff_w, aff_b,
                                          rl_w1, rl_b1, rl_w2, rl_b2, out);
}